// Round 1
// baseline (972.139 us; speedup 1.0000x reference)
//
#include <hip/hip_runtime.h>
#include <math.h>

// NonLocalBlock: B=4, C=256, Cb=128, H=W=64, N=HW=4096.
// All reference reshapes are raw row-major reinterpretations of flat buffers:
//   theta/g conv out (Cb,HW) flat == (N,Cb) row-major; phi == (Cb,N) row-major.
// Pipeline (all fp32 vector ALU, round 1 = correctness + decent tiling):
//   k1: tpg[b] = Wcat(384x256) @ x[b](256x4096) + bias          -> ws
//   k2: per-column (over n) online max/sumexp of S = Theta @ Phi (split n in 2 halves)
//   k3: y = softmax_col(S) @ G, flash-style S recompute          (split m in 2 halves)
//   k4: out = Ww(256x128) @ (y0+y1) + Wb + x
// ws requirement: 10,551,296 floats = 42.3 MB.

constexpr int CI = 256;     // input channels
constexpr int CB = 128;     // bottleneck channels
constexpr int HWD = 4096;   // H*W
constexpr int NBATCH = 4;
constexpr int NN_ = 4096;   // N
constexpr long long TPG_BATCH = 3LL * CB * HWD;                   // 1572864
constexpr long long OFF_TPG = 0;
constexpr long long OFF_CMAX = (long long)NBATCH * TPG_BATCH;     // 6291456
constexpr long long OFF_CSUM = OFF_CMAX + 2LL * NBATCH * NN_;     // +32768
constexpr long long OFF_Y    = OFF_CSUM + 2LL * NBATCH * NN_;     // +32768

// ---------------- k1: fused theta/phi/g 1x1 convs (GEMM 384x4096, K=256) ----
__global__ __launch_bounds__(256) void k1_conv_tpg(
    const float* __restrict__ x,
    const float* __restrict__ tw, const float* __restrict__ tb,
    const float* __restrict__ pw, const float* __restrict__ pb,
    const float* __restrict__ gw, const float* __restrict__ gb,
    float* __restrict__ ws)
{
    __shared__ float As[64 * 68];   // A tile transposed [k][m]
    __shared__ float Bs[64 * 68];   // B tile [k][n]
    const int t  = threadIdx.x;
    const int tx = t & 15, ty = t >> 4;
    const int hw0 = blockIdx.x * 64;
    const int j0  = blockIdx.y * 64;   // 0..383 over {theta,phi,g} rows
    const int b   = blockIdx.z;
    const int matId = j0 >> 7;         // 0:theta 1:phi 2:g (64 | 128)
    const float* wmat = (matId == 0) ? tw : (matId == 1) ? pw : gw;
    const float* bvec = (matId == 0) ? tb : (matId == 1) ? pb : gb;
    const int jl0 = j0 & 127;
    const float* xb = x + (size_t)b * CI * HWD;

    float acc[4][4] = {};
    for (int k0 = 0; k0 < CI; k0 += 64) {
        #pragma unroll
        for (int i = 0; i < 4; i++) {
            int flat4 = i * 256 + t;
            int row = flat4 >> 4, k4 = flat4 & 15;
            float4 f = *(const float4*)&wmat[(size_t)(jl0 + row) * CI + k0 + k4 * 4];
            As[(k4 * 4 + 0) * 68 + row] = f.x;
            As[(k4 * 4 + 1) * 68 + row] = f.y;
            As[(k4 * 4 + 2) * 68 + row] = f.z;
            As[(k4 * 4 + 3) * 68 + row] = f.w;
        }
        #pragma unroll
        for (int i = 0; i < 4; i++) {
            int flat4 = i * 256 + t;
            int krow = flat4 >> 4, c4 = flat4 & 15;
            *(float4*)&Bs[krow * 68 + c4 * 4] =
                *(const float4*)&xb[(size_t)(k0 + krow) * HWD + hw0 + c4 * 4];
        }
        __syncthreads();
        #pragma unroll 8
        for (int k = 0; k < 64; k++) {
            float4 a4 = *(const float4*)&As[k * 68 + ty * 4];
            float4 b4 = *(const float4*)&Bs[k * 68 + tx * 4];
            float af[4] = {a4.x, a4.y, a4.z, a4.w};
            float bf[4] = {b4.x, b4.y, b4.z, b4.w};
            #pragma unroll
            for (int i = 0; i < 4; i++)
                #pragma unroll
                for (int j = 0; j < 4; j++)
                    acc[i][j] += af[i] * bf[j];
        }
        __syncthreads();
    }
    float* outp = ws + OFF_TPG + (size_t)b * TPG_BATCH;
    #pragma unroll
    for (int i = 0; i < 4; i++) {
        int j = j0 + ty * 4 + i;
        float bias = bvec[jl0 + ty * 4 + i];
        float4 v;
        v.x = acc[i][0] + bias; v.y = acc[i][1] + bias;
        v.z = acc[i][2] + bias; v.w = acc[i][3] + bias;
        *(float4*)&outp[(size_t)j * HWD + hw0 + tx * 4] = v;
    }
}

// ---------------- k2: column-wise (over n) online softmax stats -------------
// Block: 64 columns m, iterates one n-half (2048 rows). Partial (M,S) per half.
__global__ __launch_bounds__(256) void k2_colstats(float* __restrict__ ws)
{
    __shared__ float R1[64 * 68];    // theta k-half tile transposed / S tile
    __shared__ float Bs[128 * 68];   // phi tile [k][m], persistent
    __shared__ float part[256];
    __shared__ float runM[64], runS[64], nM[64];
    const int t = threadIdx.x, tx = t & 15, ty = t >> 4;
    const int m0   = blockIdx.x * 64;
    const int half = blockIdx.y;
    const int b    = blockIdx.z;
    const float* theta = ws + (size_t)b * TPG_BATCH;     // view (4096 x 128)
    const float* phi   = theta + (size_t)CB * HWD;       // view (128 x 4096)

    #pragma unroll
    for (int i = 0; i < 8; i++) {
        int flat4 = i * 256 + t;
        int krow = flat4 >> 4, c4 = flat4 & 15;
        *(float4*)&Bs[krow * 68 + c4 * 4] =
            *(const float4*)&phi[(size_t)krow * HWD + m0 + c4 * 4];
    }
    if (t < 64) { runM[t] = -INFINITY; runS[t] = 0.f; }
    __syncthreads();

    const int nBeg = half * 2048, nEnd = nBeg + 2048;
    for (int n0 = nBeg; n0 < nEnd; n0 += 64) {
        float acc[4][4] = {};
        for (int kh = 0; kh < 2; kh++) {
            #pragma unroll
            for (int i = 0; i < 4; i++) {
                int flat4 = i * 256 + t;
                int nrow = flat4 >> 4, k4 = flat4 & 15;
                float4 f = *(const float4*)&theta[(size_t)(n0 + nrow) * CB + kh * 64 + k4 * 4];
                R1[(k4 * 4 + 0) * 68 + nrow] = f.x;
                R1[(k4 * 4 + 1) * 68 + nrow] = f.y;
                R1[(k4 * 4 + 2) * 68 + nrow] = f.z;
                R1[(k4 * 4 + 3) * 68 + nrow] = f.w;
            }
            __syncthreads();
            #pragma unroll 8
            for (int k = 0; k < 64; k++) {
                float4 a4 = *(const float4*)&R1[k * 68 + ty * 4];
                float4 b4 = *(const float4*)&Bs[(kh * 64 + k) * 68 + tx * 4];
                float af[4] = {a4.x, a4.y, a4.z, a4.w};
                float bf[4] = {b4.x, b4.y, b4.z, b4.w};
                #pragma unroll
                for (int i = 0; i < 4; i++)
                    #pragma unroll
                    for (int j = 0; j < 4; j++)
                        acc[i][j] += af[i] * bf[j];
            }
            __syncthreads();
        }
        // stage S tile (64n x 64m) into R1 (theta tile dead until next n0)
        #pragma unroll
        for (int i = 0; i < 4; i++) {
            float4 v = make_float4(acc[i][0], acc[i][1], acc[i][2], acc[i][3]);
            *(float4*)&R1[(ty * 4 + i) * 68 + tx * 4] = v;
        }
        __syncthreads();
        {   // partial max over 16-row segments
            int col = t & 63, seg = t >> 6;
            float mx = -INFINITY;
            #pragma unroll
            for (int r = 0; r < 16; r++) mx = fmaxf(mx, R1[(seg * 16 + r) * 68 + col]);
            part[seg * 64 + col] = mx;
        }
        __syncthreads();
        if (t < 64) {
            float mx = fmaxf(fmaxf(part[t], part[64 + t]), fmaxf(part[128 + t], part[192 + t]));
            nM[t] = fmaxf(runM[t], mx);
        }
        __syncthreads();
        {   // partial sumexp with updated max
            int col = t & 63, seg = t >> 6;
            float nm = nM[col];
            float s = 0.f;
            #pragma unroll
            for (int r = 0; r < 16; r++) s += __expf(R1[(seg * 16 + r) * 68 + col] - nm);
            part[seg * 64 + col] = s;
        }
        __syncthreads();
        if (t < 64) {
            float ts = part[t] + part[64 + t] + part[128 + t] + part[192 + t];
            runS[t] = runS[t] * __expf(runM[t] - nM[t]) + ts;
            runM[t] = nM[t];
        }
        __syncthreads();
    }
    if (t < 64) {
        ws[OFF_CMAX + ((size_t)half * NBATCH + b) * NN_ + m0 + t] = runM[t];
        ws[OFF_CSUM + ((size_t)half * NBATCH + b) * NN_ + m0 + t] = runS[t];
    }
}

// ---------------- k3: y = softmax_col(S) @ G, flash-style -------------------
// Block: 64 rows n (all 128 c), iterates one m-half (2048 cols). Writes partial y.
__global__ __launch_bounds__(256) void k3_attn_y(float* __restrict__ ws)
{
    __shared__ float R1[64 * 68];    // theta k-half tile transposed -> P tile [m][n]
    __shared__ float R2[128 * 68];   // phi tile [k][m] -> G tile [m][c] (ld 132)
    __shared__ float cm[64], cr[64];
    const int t = threadIdx.x, tx = t & 15, ty = t >> 4;
    const int n0   = blockIdx.x * 64;
    const int half = blockIdx.y;
    const int b    = blockIdx.z;
    const float* theta = ws + (size_t)b * TPG_BATCH;
    const float* phi   = theta + (size_t)CB * HWD;
    const float* g     = theta + 2LL * CB * HWD;         // view (4096 x 128)

    float yacc[4][8] = {};
    const int mBeg = half * 2048, mEnd = mBeg + 2048;
    for (int m0 = mBeg; m0 < mEnd; m0 += 64) {
        __syncthreads();   // previous iteration's PV reads of R1/R2/cm done
        #pragma unroll
        for (int i = 0; i < 8; i++) {
            int flat4 = i * 256 + t;
            int krow = flat4 >> 4, c4 = flat4 & 15;
            *(float4*)&R2[krow * 68 + c4 * 4] =
                *(const float4*)&phi[(size_t)krow * HWD + m0 + c4 * 4];
        }
        if (t < 64) {   // merge the two n-half partial stats analytically
            int m = m0 + t;
            float M1 = ws[OFF_CMAX + (size_t)b * NN_ + m];
            float M2 = ws[OFF_CMAX + ((size_t)NBATCH + b) * NN_ + m];
            float S1 = ws[OFF_CSUM + (size_t)b * NN_ + m];
            float S2 = ws[OFF_CSUM + ((size_t)NBATCH + b) * NN_ + m];
            float M = fmaxf(M1, M2);
            float S = S1 * __expf(M1 - M) + S2 * __expf(M2 - M);
            cm[t] = M;
            cr[t] = 1.0f / S;
        }
        float sacc[4][4] = {};
        for (int kh = 0; kh < 2; kh++) {
            #pragma unroll
            for (int i = 0; i < 4; i++) {
                int flat4 = i * 256 + t;
                int nrow = flat4 >> 4, k4 = flat4 & 15;
                float4 f = *(const float4*)&theta[(size_t)(n0 + nrow) * CB + kh * 64 + k4 * 4];
                R1[(k4 * 4 + 0) * 68 + nrow] = f.x;
                R1[(k4 * 4 + 1) * 68 + nrow] = f.y;
                R1[(k4 * 4 + 2) * 68 + nrow] = f.z;
                R1[(k4 * 4 + 3) * 68 + nrow] = f.w;
            }
            __syncthreads();
            #pragma unroll 8
            for (int k = 0; k < 64; k++) {
                float4 a4 = *(const float4*)&R1[k * 68 + ty * 4];
                float4 b4 = *(const float4*)&R2[(kh * 64 + k) * 68 + tx * 4];
                float af[4] = {a4.x, a4.y, a4.z, a4.w};
                float bf[4] = {b4.x, b4.y, b4.z, b4.w};
                #pragma unroll
                for (int i = 0; i < 4; i++)
                    #pragma unroll
                    for (int j = 0; j < 4; j++)
                        sacc[i][j] += af[i] * bf[j];
            }
            __syncthreads();
        }
        // write P (transposed [m][n]) into R1; load G into R2 (both tiles dead)
        #pragma unroll
        for (int j = 0; j < 4; j++) {
            float M = cm[tx * 4 + j], R = cr[tx * 4 + j];
            #pragma unroll
            for (int i = 0; i < 4; i++)
                R1[(tx * 4 + j) * 68 + ty * 4 + i] = __expf(sacc[i][j] - M) * R;
        }
        #pragma unroll
        for (int i = 0; i < 8; i++) {
            int flat4 = i * 256 + t;
            int mrow = flat4 >> 5, c4 = flat4 & 31;
            *(float4*)&R2[mrow * 132 + c4 * 4] =
                *(const float4*)&g[(size_t)(m0 + mrow) * CB + c4 * 4];
        }
        __syncthreads();
        #pragma unroll 4
        for (int k2 = 0; k2 < 64; k2++) {
            float4 a4 = *(const float4*)&R1[k2 * 68 + ty * 4];
            float4 g0 = *(const float4*)&R2[k2 * 132 + tx * 8];
            float4 g1 = *(const float4*)&R2[k2 * 132 + tx * 8 + 4];
            float af[4] = {a4.x, a4.y, a4.z, a4.w};
            float gf[8] = {g0.x, g0.y, g0.z, g0.w, g1.x, g1.y, g1.z, g1.w};
            #pragma unroll
            for (int i = 0; i < 4; i++)
                #pragma unroll
                for (int j = 0; j < 8; j++)
                    yacc[i][j] += af[i] * gf[j];
        }
    }
    float* y = ws + OFF_Y + ((size_t)half * NBATCH + b) * CB * HWD;
    #pragma unroll
    for (int i = 0; i < 4; i++) {
        float4 v0 = make_float4(yacc[i][0], yacc[i][1], yacc[i][2], yacc[i][3]);
        float4 v1 = make_float4(yacc[i][4], yacc[i][5], yacc[i][6], yacc[i][7]);
        size_t base = (size_t)(n0 + ty * 4 + i) * CB + tx * 8;
        *(float4*)&y[base] = v0;
        *(float4*)&y[base + 4] = v1;
    }
}

// ---------------- k4: out = Ww @ (y0+y1) + Wb + x ---------------------------
__global__ __launch_bounds__(256) void k4_outconv(
    const float* __restrict__ x, const float* __restrict__ Ww,
    const float* __restrict__ Wb, const float* __restrict__ ws,
    float* __restrict__ out)
{
    __shared__ float As[64 * 68];
    __shared__ float Bs[64 * 68];
    const int t = threadIdx.x, tx = t & 15, ty = t >> 4;
    const int hw0 = blockIdx.x * 64;
    const int o0  = blockIdx.y * 64;
    const int b   = blockIdx.z;
    const float* y0 = ws + OFF_Y + (size_t)b * CB * HWD;             // (128 x 4096)
    const float* y1 = ws + OFF_Y + ((size_t)NBATCH + b) * CB * HWD;

    float acc[4][4] = {};
    for (int kh = 0; kh < 2; kh++) {
        #pragma unroll
        for (int i = 0; i < 4; i++) {
            int flat4 = i * 256 + t;
            int row = flat4 >> 4, k4 = flat4 & 15;
            float4 f = *(const float4*)&Ww[(size_t)(o0 + row) * CB + kh * 64 + k4 * 4];
            As[(k4 * 4 + 0) * 68 + row] = f.x;
            As[(k4 * 4 + 1) * 68 + row] = f.y;
            As[(k4 * 4 + 2) * 68 + row] = f.z;
            As[(k4 * 4 + 3) * 68 + row] = f.w;
        }
        #pragma unroll
        for (int i = 0; i < 4; i++) {
            int flat4 = i * 256 + t;
            int krow = flat4 >> 4, c4 = flat4 & 15;
            size_t idx = (size_t)(kh * 64 + krow) * HWD + hw0 + c4 * 4;
            float4 fa = *(const float4*)&y0[idx];
            float4 fb = *(const float4*)&y1[idx];
            fa.x += fb.x; fa.y += fb.y; fa.z += fb.z; fa.w += fb.w;
            *(float4*)&Bs[krow * 68 + c4 * 4] = fa;
        }
        __syncthreads();
        #pragma unroll 8
        for (int k = 0; k < 64; k++) {
            float4 a4 = *(const float4*)&As[k * 68 + ty * 4];
            float4 b4 = *(const float4*)&Bs[k * 68 + tx * 4];
            float af[4] = {a4.x, a4.y, a4.z, a4.w};
            float bf[4] = {b4.x, b4.y, b4.z, b4.w};
            #pragma unroll
            for (int i = 0; i < 4; i++)
                #pragma unroll
                for (int j = 0; j < 4; j++)
                    acc[i][j] += af[i] * bf[j];
        }
        __syncthreads();
    }
    #pragma unroll
    for (int i = 0; i < 4; i++) {
        int o = o0 + ty * 4 + i;
        float bias = Wb[o];
        size_t idx = (size_t)b * CI * HWD + (size_t)o * HWD + hw0 + tx * 4;
        float4 xr = *(const float4*)&x[idx];
        float4 v;
        v.x = acc[i][0] + bias + xr.x;
        v.y = acc[i][1] + bias + xr.y;
        v.z = acc[i][2] + bias + xr.z;
        v.w = acc[i][3] + bias + xr.w;
        *(float4*)&out[idx] = v;
    }
}

extern "C" void kernel_launch(void* const* d_in, const int* in_sizes, int n_in,
                              void* d_out, int out_size, void* d_ws, size_t ws_size,
                              hipStream_t stream)
{
    const float* x  = (const float*)d_in[0];
    const float* tw = (const float*)d_in[1];
    const float* tb = (const float*)d_in[2];
    const float* pw = (const float*)d_in[3];
    const float* pb = (const float*)d_in[4];
    const float* gw = (const float*)d_in[5];
    const float* gb = (const float*)d_in[6];
    const float* Ww = (const float*)d_in[7];
    const float* Wb = (const float*)d_in[8];
    float* ws  = (float*)d_ws;
    float* out = (float*)d_out;
    dim3 blk(256, 1, 1);
    // needs ws_size >= 42.3 MB (10,551,296 floats)
    hipLaunchKernelGGL(k1_conv_tpg, dim3(64, 6, NBATCH), blk, 0, stream,
                       x, tw, tb, pw, pb, gw, gb, ws);
    hipLaunchKernelGGL(k2_colstats, dim3(64, 2, NBATCH), blk, 0, stream, ws);
    hipLaunchKernelGGL(k3_attn_y,  dim3(64, 2, NBATCH), blk, 0, stream, ws);
    hipLaunchKernelGGL(k4_outconv, dim3(64, 4, NBATCH), blk, 0, stream,
                       x, Ww, Wb, ws, out);
}

// Round 3
// 355.603 us; speedup vs baseline: 2.7338x; 2.7338x over previous
//
#include <hip/hip_runtime.h>
#include <math.h>

// NonLocalBlock: B=4, C=256, Cb=128, H=W=64, N=HW=4096.
// Round 3: fix the reshape-vs-transpose scramble from round 2.
//   Reference reshapes are RAW reinterpretations of flat conv buffers:
//     theta_m[n][k] = theta_conv_flat[n*128+k]   (store plain, read flat)
//     phi_m[k][m]   = phi_conv_flat[k*4096+m]    (identity; phiT = real transpose)
//     Gm[m][c]      = g_conv_flat[m*128+c]       (store plain; gT built by k1b)
//     y out buffer  = yflat[n*128+c] reinterpreted by k4 as (Cb,HW)
// Pipeline:
//   k1 : fp32 GEMM tpg = Wcat(384x256) @ x; bf16 stores (theta/g plain, phiT transposed)
//   k1b: gT[c][m] = gflat[m*128+c]  (bf16 transpose, 8MB)
//   k2 : D[m] = sum_n exp(S[n][m]),  S = theta_m @ phi_m   (16x16x32 bf16 MFMA)
//   k3 : y[n][c] = sum_m exp(S[n][m])/D[m] * Gm[m][c]      (flash-style, P via LDS)
//   k4 : out = Ww @ y_conv + Wb + x  (fp32)
// ws: 16MB bf16 + D 128KB + Y 16MB = 33.7MB.

constexpr int CI = 256;
constexpr int CB = 128;
constexpr int HWD = 4096;
constexpr int NBATCH = 4;
constexpr int NN_ = 4096;
// ushort-unit offsets
constexpr size_t U_THETA = 0;
constexpr size_t U_PHIT  = (size_t)NBATCH * NN_ * CB;       // 2,097,152
constexpr size_t U_G     = 2 * U_PHIT;                      // 4,194,304
constexpr size_t U_GT    = 3 * U_PHIT;                      // 6,291,456
// float-unit offsets (after 8,388,608 ushorts = 16,777,216 B)
constexpr size_t F_D = 4194304;
constexpr size_t F_Y = F_D + 2ull * NBATCH * NN_;           // 4,227,072

typedef short v8s __attribute__((ext_vector_type(8)));
typedef float v4f __attribute__((ext_vector_type(4)));
#define MFMA16(a, b, c) __builtin_amdgcn_mfma_f32_16x16x32_bf16(a, b, c, 0, 0, 0)

__device__ __forceinline__ unsigned short f2bf(float f) {
    union { float f; unsigned u; } v; v.f = f;
    unsigned r = v.u + 0x7fff + ((v.u >> 16) & 1);
    return (unsigned short)(r >> 16);
}

// ---------------- k1: fused theta/phi/g 1x1 convs, fp32 compute, bf16 out ---
__global__ __launch_bounds__(256) void k1_conv_tpg(
    const float* __restrict__ x,
    const float* __restrict__ tw, const float* __restrict__ tb,
    const float* __restrict__ pw, const float* __restrict__ pb,
    const float* __restrict__ gw, const float* __restrict__ gb,
    unsigned short* __restrict__ thetaB, unsigned short* __restrict__ phiTB,
    unsigned short* __restrict__ gB)
{
    __shared__ float As[64 * 68];
    __shared__ float Bs[64 * 68];
    const int t  = threadIdx.x;
    const int tx = t & 15, ty = t >> 4;
    const int hw0 = blockIdx.x * 64;
    const int j0  = blockIdx.y * 64;
    const int b   = blockIdx.z;
    const int matId = j0 >> 7;
    const float* wmat = (matId == 0) ? tw : (matId == 1) ? pw : gw;
    const float* bvec = (matId == 0) ? tb : (matId == 1) ? pb : gb;
    const int jl0 = j0 & 127;
    const float* xb = x + (size_t)b * CI * HWD;

    float acc[4][4] = {};
    for (int k0 = 0; k0 < CI; k0 += 64) {
        #pragma unroll
        for (int i = 0; i < 4; i++) {
            int flat4 = i * 256 + t;
            int row = flat4 >> 4, k4 = flat4 & 15;
            float4 f = *(const float4*)&wmat[(size_t)(jl0 + row) * CI + k0 + k4 * 4];
            As[(k4 * 4 + 0) * 68 + row] = f.x;
            As[(k4 * 4 + 1) * 68 + row] = f.y;
            As[(k4 * 4 + 2) * 68 + row] = f.z;
            As[(k4 * 4 + 3) * 68 + row] = f.w;
        }
        #pragma unroll
        for (int i = 0; i < 4; i++) {
            int flat4 = i * 256 + t;
            int krow = flat4 >> 4, c4 = flat4 & 15;
            *(float4*)&Bs[krow * 68 + c4 * 4] =
                *(const float4*)&xb[(size_t)(k0 + krow) * HWD + hw0 + c4 * 4];
        }
        __syncthreads();
        #pragma unroll 8
        for (int k = 0; k < 64; k++) {
            float4 a4 = *(const float4*)&As[k * 68 + ty * 4];
            float4 b4 = *(const float4*)&Bs[k * 68 + tx * 4];
            float af[4] = {a4.x, a4.y, a4.z, a4.w};
            float bf[4] = {b4.x, b4.y, b4.z, b4.w};
            #pragma unroll
            for (int i = 0; i < 4; i++)
                #pragma unroll
                for (int j = 0; j < 4; j++)
                    acc[i][j] += af[i] * bf[j];
        }
        __syncthreads();
    }
    if (matId == 1) {
        // phi needs the REAL transpose: phiT[m=hw][k=cb]
        unsigned short* dst = phiTB + (size_t)b * NN_ * CB;
        float bi[4];
        #pragma unroll
        for (int i = 0; i < 4; i++) bi[i] = bvec[jl0 + ty * 4 + i];
        #pragma unroll
        for (int j = 0; j < 4; j++) {
            int hw = hw0 + tx * 4 + j;
            ushort4 v;
            v.x = f2bf(acc[0][j] + bi[0]);
            v.y = f2bf(acc[1][j] + bi[1]);
            v.z = f2bf(acc[2][j] + bi[2]);
            v.w = f2bf(acc[3][j] + bi[3]);
            *(ushort4*)&dst[(size_t)hw * CB + jl0 + ty * 4] = v;
        }
    } else {
        // theta / g: PLAIN conv-layout flat store (reference reinterprets raw)
        unsigned short* dst = ((matId == 0) ? thetaB : gB) + (size_t)b * CB * HWD;
        #pragma unroll
        for (int i = 0; i < 4; i++) {
            int cb = jl0 + ty * 4 + i;
            float bias = bvec[cb];
            ushort4 v;
            v.x = f2bf(acc[i][0] + bias);
            v.y = f2bf(acc[i][1] + bias);
            v.z = f2bf(acc[i][2] + bias);
            v.w = f2bf(acc[i][3] + bias);
            *(ushort4*)&dst[(size_t)cb * HWD + hw0 + tx * 4] = v;
        }
    }
}

// ---------------- k1b: gT[c][m] = gflat[m*128+c] ----------------------------
// Coalesced reads (64 lanes = one 128B row segment), ushort8 packed stores.
__global__ __launch_bounds__(256) void k1b_transpose_g(
    const unsigned short* __restrict__ gB, unsigned short* __restrict__ gTB)
{
    const int t = threadIdx.x;
    const int m0 = blockIdx.x * 32;
    const int c0 = blockIdx.y * 64;
    const int b  = blockIdx.z;
    const unsigned short* src = gB + (size_t)b * CB * HWD;
    unsigned short* dst = gTB + (size_t)b * CB * HWD;
    const int c = c0 + (t & 63);
    const int mseg = (t >> 6) * 8;
    ushort8_t_pack: ;
    unsigned short v[8];
    #pragma unroll
    for (int j = 0; j < 8; j++)
        v[j] = src[(size_t)(m0 + mseg + j) * CB + c];
    typedef unsigned short u8s __attribute__((ext_vector_type(8)));
    u8s pack;
    #pragma unroll
    for (int j = 0; j < 8; j++) pack[j] = v[j];
    *(u8s*)&dst[(size_t)c * HWD + m0 + mseg] = pack;
}

// ---------------- k2: D[m] = sum_n exp(S[n][m]) via MFMA --------------------
__global__ __launch_bounds__(256) void k2_colsum(
    const unsigned short* __restrict__ thetaB,
    const unsigned short* __restrict__ phiTB,
    float* __restrict__ Dout)
{
    __shared__ float part[4][64];
    const int t = threadIdx.x;
    const int lane = t & 63, w = t >> 6;
    const int ln = lane & 15, quad = lane >> 4;
    const int m0 = blockIdx.x * 64, half = blockIdx.y, b = blockIdx.z;
    const unsigned short* th = thetaB + (size_t)b * NN_ * CB;  // theta_m[n][k] flat
    const unsigned short* ph = phiTB + (size_t)b * NN_ * CB;   // phiT[m][k]

    v8s bf[4][4];
    #pragma unroll
    for (int mt = 0; mt < 4; mt++)
        #pragma unroll
        for (int kt = 0; kt < 4; kt++)
            bf[mt][kt] = *(const v8s*)&ph[(size_t)(m0 + mt * 16 + ln) * CB + kt * 32 + quad * 8];

    float dsum[4] = {0.f, 0.f, 0.f, 0.f};
    const int nEnd = half * 2048 + 2048;
    for (int n0 = half * 2048 + w * 16; n0 < nEnd; n0 += 64) {
        v8s af[4];
        #pragma unroll
        for (int kt = 0; kt < 4; kt++)
            af[kt] = *(const v8s*)&th[(size_t)(n0 + ln) * CB + kt * 32 + quad * 8];
        v4f s[4] = {};
        #pragma unroll
        for (int mt = 0; mt < 4; mt++)
            #pragma unroll
            for (int kt = 0; kt < 4; kt++)
                s[mt] = MFMA16(af[kt], bf[mt][kt], s[mt]);
        #pragma unroll
        for (int mt = 0; mt < 4; mt++)
            #pragma unroll
            for (int r = 0; r < 4; r++)
                dsum[mt] += __expf(s[mt][r]);
    }
    #pragma unroll
    for (int mt = 0; mt < 4; mt++) {
        float v = dsum[mt];
        v += __shfl_xor(v, 16);
        v += __shfl_xor(v, 32);
        dsum[mt] = v;
    }
    if (quad == 0) {
        #pragma unroll
        for (int mt = 0; mt < 4; mt++) part[w][mt * 16 + ln] = dsum[mt];
    }
    __syncthreads();
    if (t < 64) {
        float v = part[0][t] + part[1][t] + part[2][t] + part[3][t];
        Dout[((size_t)half * NBATCH + b) * NN_ + m0 + t] = v;
    }
}

// ---------------- k3: y[n][c] = sum_m P[n][m] Gm[m][c] ----------------------
// grid (64 n-blocks, 2 m-halves, B). Block: 64 n x 128 c output (partial y).
__global__ __launch_bounds__(256) void k3_attn(
    const unsigned short* __restrict__ thetaB,
    const unsigned short* __restrict__ phiTB,
    const unsigned short* __restrict__ gTB,
    const float* __restrict__ D, float* __restrict__ Y)
{
    __shared__ unsigned short Pl[64][72];   // [n][m], 144B rows (16B aligned)
    const int t = threadIdx.x;
    const int lane = t & 63, w = t >> 6;
    const int ln = lane & 15, quad = lane >> 4;
    const int n0 = blockIdx.x * 64, half = blockIdx.y, b = blockIdx.z;
    const unsigned short* th = thetaB + (size_t)b * NN_ * CB;
    const unsigned short* ph = phiTB + (size_t)b * NN_ * CB;
    const unsigned short* gT = gTB + (size_t)b * CB * HWD;     // gT[c][m]
    const float* D0 = D + (size_t)b * NN_;
    const float* D1 = D + ((size_t)NBATCH + b) * NN_;

    // persistent theta A-frags for this wave's 16 n-rows
    v8s ath[4];
    #pragma unroll
    for (int kt = 0; kt < 4; kt++)
        ath[kt] = *(const v8s*)&th[(size_t)(n0 + w * 16 + ln) * CB + kt * 32 + quad * 8];

    v4f yacc[2][4] = {};   // [ct: c-16-tile][nt: n-16-tile]
    const int mEnd = half * 2048 + 2048;
    for (int m0 = half * 2048; m0 < mEnd; m0 += 64) {
        // S phase: wave computes S[n0+w*16 .. +15][m0 .. m0+63]
        v4f s[4] = {};
        #pragma unroll
        for (int mt = 0; mt < 4; mt++) {
            #pragma unroll
            for (int kt = 0; kt < 4; kt++) {
                v8s bphi = *(const v8s*)&ph[(size_t)(m0 + mt * 16 + ln) * CB + kt * 32 + quad * 8];
                s[mt] = MFMA16(ath[kt], bphi, s[mt]);
            }
        }
        float ri[4];
        #pragma unroll
        for (int mt = 0; mt < 4; mt++) {
            int m = m0 + mt * 16 + ln;
            ri[mt] = __builtin_amdgcn_rcpf(D0[m] + D1[m]);
        }
        __syncthreads();   // prior iteration's PV reads of Pl complete
        #pragma unroll
        for (int mt = 0; mt < 4; mt++)
            #pragma unroll
            for (int r = 0; r < 4; r++)
                Pl[w * 16 + quad * 4 + r][mt * 16 + ln] = f2bf(__expf(s[mt][r]) * ri[mt]);
        __syncthreads();
        // PV phase: wave computes c-rows w*32..w*32+31, all 64 n of the block
        #pragma unroll
        for (int ct = 0; ct < 2; ct++) {
            #pragma unroll
            for (int kt2 = 0; kt2 < 2; kt2++) {
                v8s bg = *(const v8s*)&gT[(size_t)(w * 32 + ct * 16 + ln) * HWD + m0 + kt2 * 32 + quad * 8];
                #pragma unroll
                for (int nt = 0; nt < 4; nt++) {
                    v8s ap = *(const v8s*)&Pl[nt * 16 + ln][kt2 * 32 + quad * 8];
                    yacc[ct][nt] = MFMA16(ap, bg, yacc[ct][nt]);
                }
            }
        }
    }
    // D tile: row = n (quad*4+r), col = c (ln). Store yflat[n*128+c].
    float* yp = Y + ((size_t)half * NBATCH + b) * CB * HWD;
    #pragma unroll
    for (int ct = 0; ct < 2; ct++)
        #pragma unroll
        for (int nt = 0; nt < 4; nt++)
            #pragma unroll
            for (int r = 0; r < 4; r++)
                yp[(size_t)(n0 + nt * 16 + quad * 4 + r) * CB + w * 32 + ct * 16 + ln] =
                    yacc[ct][nt][r];
}

// ---------------- k4: out = Ww @ (y0+y1) + Wb + x ---------------------------
__global__ __launch_bounds__(256) void k4_outconv(
    const float* __restrict__ x, const float* __restrict__ Ww,
    const float* __restrict__ Wb, const float* __restrict__ Ybuf,
    float* __restrict__ out)
{
    __shared__ float As[64 * 68];
    __shared__ float Bs[64 * 68];
    const int t = threadIdx.x, tx = t & 15, ty = t >> 4;
    const int hw0 = blockIdx.x * 64;
    const int o0  = blockIdx.y * 64;
    const int b   = blockIdx.z;
    const float* y0 = Ybuf + (size_t)b * CB * HWD;             // yflat as (Cb,HW)
    const float* y1 = Ybuf + ((size_t)NBATCH + b) * CB * HWD;

    float acc[4][4] = {};
    for (int kh = 0; kh < 2; kh++) {
        #pragma unroll
        for (int i = 0; i < 4; i++) {
            int flat4 = i * 256 + t;
            int row = flat4 >> 4, k4 = flat4 & 15;
            float4 f = *(const float4*)&Ww[(size_t)(o0 + row) * CB + kh * 64 + k4 * 4];
            As[(k4 * 4 + 0) * 68 + row] = f.x;
            As[(k4 * 4 + 1) * 68 + row] = f.y;
            As[(k4 * 4 + 2) * 68 + row] = f.z;
            As[(k4 * 4 + 3) * 68 + row] = f.w;
        }
        #pragma unroll
        for (int i = 0; i < 4; i++) {
            int flat4 = i * 256 + t;
            int krow = flat4 >> 4, c4 = flat4 & 15;
            size_t idx = (size_t)(kh * 64 + krow) * HWD + hw0 + c4 * 4;
            float4 fa = *(const float4*)&y0[idx];
            float4 fb = *(const float4*)&y1[idx];
            fa.x += fb.x; fa.y += fb.y; fa.z += fb.z; fa.w += fb.w;
            *(float4*)&Bs[krow * 68 + c4 * 4] = fa;
        }
        __syncthreads();
        #pragma unroll 8
        for (int k = 0; k < 64; k++) {
            float4 a4 = *(const float4*)&As[k * 68 + ty * 4];
            float4 b4 = *(const float4*)&Bs[k * 68 + tx * 4];
            float af[4] = {a4.x, a4.y, a4.z, a4.w};
            float bf[4] = {b4.x, b4.y, b4.z, b4.w};
            #pragma unroll
            for (int i = 0; i < 4; i++)
                #pragma unroll
                for (int j = 0; j < 4; j++)
                    acc[i][j] += af[i] * bf[j];
        }
        __syncthreads();
    }
    #pragma unroll
    for (int i = 0; i < 4; i++) {
        int o = o0 + ty * 4 + i;
        float bias = Wb[o];
        size_t idx = (size_t)b * CI * HWD + (size_t)o * HWD + hw0 + tx * 4;
        float4 xr = *(const float4*)&x[idx];
        float4 v;
        v.x = acc[i][0] + bias + xr.x;
        v.y = acc[i][1] + bias + xr.y;
        v.z = acc[i][2] + bias + xr.z;
        v.w = acc[i][3] + bias + xr.w;
        *(float4*)&out[idx] = v;
    }
}

extern "C" void kernel_launch(void* const* d_in, const int* in_sizes, int n_in,
                              void* d_out, int out_size, void* d_ws, size_t ws_size,
                              hipStream_t stream)
{
    const float* x  = (const float*)d_in[0];
    const float* tw = (const float*)d_in[1];
    const float* tb = (const float*)d_in[2];
    const float* pw = (const float*)d_in[3];
    const float* pb = (const float*)d_in[4];
    const float* gw = (const float*)d_in[5];
    const float* gb = (const float*)d_in[6];
    const float* Ww = (const float*)d_in[7];
    const float* Wb = (const float*)d_in[8];
    unsigned short* wsu = (unsigned short*)d_ws;
    float* wsf = (float*)d_ws;
    unsigned short* thetaB = wsu + U_THETA;
    unsigned short* phiTB  = wsu + U_PHIT;
    unsigned short* gB     = wsu + U_G;
    unsigned short* gTB    = wsu + U_GT;
    float* Dbuf = wsf + F_D;
    float* Ybuf = wsf + F_Y;
    float* out = (float*)d_out;
    dim3 blk(256, 1, 1);
    hipLaunchKernelGGL(k1_conv_tpg, dim3(64, 6, NBATCH), blk, 0, stream,
                       x, tw, tb, pw, pb, gw, gb, thetaB, phiTB, gB);
    hipLaunchKernelGGL(k1b_transpose_g, dim3(128, 2, NBATCH), blk, 0, stream,
                       gB, gTB);
    hipLaunchKernelGGL(k2_colsum, dim3(64, 2, NBATCH), blk, 0, stream,
                       thetaB, phiTB, Dbuf);
    hipLaunchKernelGGL(k3_attn, dim3(64, 2, NBATCH), blk, 0, stream,
                       thetaB, phiTB, gTB, Dbuf, Ybuf);
    hipLaunchKernelGGL(k4_outconv, dim3(64, 4, NBATCH), blk, 0, stream,
                       x, Ww, Wb, Ybuf, out);
}

// Round 4
// 247.369 us; speedup vs baseline: 3.9299x; 1.4375x over previous
//
#include <hip/hip_runtime.h>
#include <math.h>

// NonLocalBlock: B=4, C=256, Cb=128, H=W=64, N=HW=4096.
// Round 4: latency attack on k2/k3 (round-3 counters: MfmaUtil 8%, all pipes idle).
//   k1 : fp32 GEMM tpg = Wcat(384x256) @ x; bf16 stores (theta/g plain, phiT transposed)
//   k2 : D[m] = sum_n exp(S[n][m]) via MFMA; n split in 4 quarters, A-frag prefetch
//   k1b: gT[c][m] = gflat[m*128+c] / D[m]  (transpose + softmax denom prescale)
//   k3 : y[n][c] = sum_m exp(S[n][m]) * gT[c][m]; phi tile via LDS (shared by 4 waves,
//        reg->LDS prefetch pipeline), m split in 4 quarters, bf16 partial-Y out
//   k4 : out = Ww @ (sum of 4 bf16 Y partials) + Wb + x  (fp32)
// ws: ushort[16M] = 32 MB (theta/phiT/g/gT 2M each + Y 8M) + D 256 KB = 32.3 MB.

constexpr int CI = 256;
constexpr int CB = 128;
constexpr int HWD = 4096;
constexpr int NBATCH = 4;
constexpr int NN_ = 4096;
// ushort-unit offsets
constexpr size_t U_THETA = 0;
constexpr size_t U_PHIT  = (size_t)NBATCH * NN_ * CB;       // 2,097,152
constexpr size_t U_G     = 2 * U_PHIT;
constexpr size_t U_GT    = 3 * U_PHIT;
constexpr size_t U_Y     = 4 * U_PHIT;                      // 8M ushorts (4 quarters)
// float-unit offsets (after 16M ushorts = 32 MB)
constexpr size_t F_D = 8388608;                             // 16 * 4096 floats

typedef short v8s __attribute__((ext_vector_type(8)));
typedef float v4f __attribute__((ext_vector_type(4)));
#define MFMA16(a, b, c) __builtin_amdgcn_mfma_f32_16x16x32_bf16(a, b, c, 0, 0, 0)

__device__ __forceinline__ unsigned short f2bf(float f) {
    union { float f; unsigned u; } v; v.f = f;
    unsigned r = v.u + 0x7fff + ((v.u >> 16) & 1);
    return (unsigned short)(r >> 16);
}
__device__ __forceinline__ float bf2f(unsigned short s) {
    union { unsigned u; float f; } v; v.u = (unsigned)s << 16;
    return v.f;
}

// ---------------- k1: fused theta/phi/g 1x1 convs, fp32 compute, bf16 out ---
__global__ __launch_bounds__(256) void k1_conv_tpg(
    const float* __restrict__ x,
    const float* __restrict__ tw, const float* __restrict__ tb,
    const float* __restrict__ pw, const float* __restrict__ pb,
    const float* __restrict__ gw, const float* __restrict__ gb,
    unsigned short* __restrict__ thetaB, unsigned short* __restrict__ phiTB,
    unsigned short* __restrict__ gB)
{
    __shared__ float As[64 * 68];
    __shared__ float Bs[64 * 68];
    const int t  = threadIdx.x;
    const int tx = t & 15, ty = t >> 4;
    const int hw0 = blockIdx.x * 64;
    const int j0  = blockIdx.y * 64;
    const int b   = blockIdx.z;
    const int matId = j0 >> 7;
    const float* wmat = (matId == 0) ? tw : (matId == 1) ? pw : gw;
    const float* bvec = (matId == 0) ? tb : (matId == 1) ? pb : gb;
    const int jl0 = j0 & 127;
    const float* xb = x + (size_t)b * CI * HWD;

    float acc[4][4] = {};
    for (int k0 = 0; k0 < CI; k0 += 64) {
        #pragma unroll
        for (int i = 0; i < 4; i++) {
            int flat4 = i * 256 + t;
            int row = flat4 >> 4, k4 = flat4 & 15;
            float4 f = *(const float4*)&wmat[(size_t)(jl0 + row) * CI + k0 + k4 * 4];
            As[(k4 * 4 + 0) * 68 + row] = f.x;
            As[(k4 * 4 + 1) * 68 + row] = f.y;
            As[(k4 * 4 + 2) * 68 + row] = f.z;
            As[(k4 * 4 + 3) * 68 + row] = f.w;
        }
        #pragma unroll
        for (int i = 0; i < 4; i++) {
            int flat4 = i * 256 + t;
            int krow = flat4 >> 4, c4 = flat4 & 15;
            *(float4*)&Bs[krow * 68 + c4 * 4] =
                *(const float4*)&xb[(size_t)(k0 + krow) * HWD + hw0 + c4 * 4];
        }
        __syncthreads();
        #pragma unroll 8
        for (int k = 0; k < 64; k++) {
            float4 a4 = *(const float4*)&As[k * 68 + ty * 4];
            float4 b4 = *(const float4*)&Bs[k * 68 + tx * 4];
            float af[4] = {a4.x, a4.y, a4.z, a4.w};
            float bf[4] = {b4.x, b4.y, b4.z, b4.w};
            #pragma unroll
            for (int i = 0; i < 4; i++)
                #pragma unroll
                for (int j = 0; j < 4; j++)
                    acc[i][j] += af[i] * bf[j];
        }
        __syncthreads();
    }
    if (matId == 1) {
        // phi: REAL transpose phiT[m=hw][k=cb]
        unsigned short* dst = phiTB + (size_t)b * NN_ * CB;
        float bi[4];
        #pragma unroll
        for (int i = 0; i < 4; i++) bi[i] = bvec[jl0 + ty * 4 + i];
        #pragma unroll
        for (int j = 0; j < 4; j++) {
            int hw = hw0 + tx * 4 + j;
            ushort4 v;
            v.x = f2bf(acc[0][j] + bi[0]);
            v.y = f2bf(acc[1][j] + bi[1]);
            v.z = f2bf(acc[2][j] + bi[2]);
            v.w = f2bf(acc[3][j] + bi[3]);
            *(ushort4*)&dst[(size_t)hw * CB + jl0 + ty * 4] = v;
        }
    } else {
        // theta / g: PLAIN conv-layout flat store
        unsigned short* dst = ((matId == 0) ? thetaB : gB) + (size_t)b * CB * HWD;
        #pragma unroll
        for (int i = 0; i < 4; i++) {
            int cb = jl0 + ty * 4 + i;
            float bias = bvec[cb];
            ushort4 v;
            v.x = f2bf(acc[i][0] + bias);
            v.y = f2bf(acc[i][1] + bias);
            v.z = f2bf(acc[i][2] + bias);
            v.w = f2bf(acc[i][3] + bias);
            *(ushort4*)&dst[(size_t)cb * HWD + hw0 + tx * 4] = v;
        }
    }
}

// ---------------- k2: D[m] = sum_n exp(S[n][m]), prefetched MFMA ------------
// grid (64 m-blocks, 4 n-quarters, B)
__global__ __launch_bounds__(256, 4) void k2_colsum(
    const unsigned short* __restrict__ thetaB,
    const unsigned short* __restrict__ phiTB,
    float* __restrict__ Dout)
{
    __shared__ float part[4][64];
    const int t = threadIdx.x;
    const int lane = t & 63, w = t >> 6;
    const int ln = lane & 15, quad = lane >> 4;
    const int m0 = blockIdx.x * 64, q = blockIdx.y, b = blockIdx.z;
    const unsigned short* th = thetaB + (size_t)b * NN_ * CB;
    const unsigned short* ph = phiTB + (size_t)b * NN_ * CB;

    v8s bf[4][4];
    #pragma unroll
    for (int mt = 0; mt < 4; mt++)
        #pragma unroll
        for (int kt = 0; kt < 4; kt++)
            bf[mt][kt] = *(const v8s*)&ph[(size_t)(m0 + mt * 16 + ln) * CB + kt * 32 + quad * 8];

    float dsum[4] = {0.f, 0.f, 0.f, 0.f};
    const int nBeg = q * 1024 + w * 16, nEnd = q * 1024 + 1024;
    v8s af[4], afn[4];
    #pragma unroll
    for (int kt = 0; kt < 4; kt++)
        af[kt] = *(const v8s*)&th[(size_t)(nBeg + ln) * CB + kt * 32 + quad * 8];
    for (int n0 = nBeg; n0 < nEnd; n0 += 64) {
        int nn = (n0 + 64 < nEnd) ? n0 + 64 : nBeg;   // clamp: harmless reload
        #pragma unroll
        for (int kt = 0; kt < 4; kt++)
            afn[kt] = *(const v8s*)&th[(size_t)(nn + ln) * CB + kt * 32 + quad * 8];
        v4f s[4] = {};
        #pragma unroll
        for (int mt = 0; mt < 4; mt++)
            #pragma unroll
            for (int kt = 0; kt < 4; kt++)
                s[mt] = MFMA16(af[kt], bf[mt][kt], s[mt]);
        #pragma unroll
        for (int mt = 0; mt < 4; mt++)
            #pragma unroll
            for (int r = 0; r < 4; r++)
                dsum[mt] += __expf(s[mt][r]);
        #pragma unroll
        for (int kt = 0; kt < 4; kt++) af[kt] = afn[kt];
    }
    #pragma unroll
    for (int mt = 0; mt < 4; mt++) {
        float v = dsum[mt];
        v += __shfl_xor(v, 16);
        v += __shfl_xor(v, 32);
        dsum[mt] = v;
    }
    if (quad == 0) {
        #pragma unroll
        for (int mt = 0; mt < 4; mt++) part[w][mt * 16 + ln] = dsum[mt];
    }
    __syncthreads();
    if (t < 64) {
        float v = part[0][t] + part[1][t] + part[2][t] + part[3][t];
        Dout[((size_t)q * NBATCH + b) * NN_ + m0 + t] = v;
    }
}

// ---------------- k1b: gT[c][m] = gflat[m*128+c] / D[m] ---------------------
__global__ __launch_bounds__(256) void k1b_transpose_scale_g(
    const unsigned short* __restrict__ gB, const float* __restrict__ D,
    unsigned short* __restrict__ gTB)
{
    const int t = threadIdx.x;
    const int m0 = blockIdx.x * 32;
    const int c0 = blockIdx.y * 64;
    const int b  = blockIdx.z;
    const unsigned short* src = gB + (size_t)b * CB * HWD;
    unsigned short* dst = gTB + (size_t)b * CB * HWD;
    const int c = c0 + (t & 63);
    const int mseg = (t >> 6) * 8;
    typedef unsigned short u8s __attribute__((ext_vector_type(8)));
    u8s pack;
    #pragma unroll
    for (int j = 0; j < 8; j++) {
        int m = m0 + mseg + j;
        float d = D[((size_t)0 * NBATCH + b) * NN_ + m]
                + D[((size_t)1 * NBATCH + b) * NN_ + m]
                + D[((size_t)2 * NBATCH + b) * NN_ + m]
                + D[((size_t)3 * NBATCH + b) * NN_ + m];
        float r = 1.0f / d;
        pack[j] = f2bf(bf2f(src[(size_t)m * CB + c]) * r);
    }
    *(u8s*)&dst[(size_t)c * HWD + m0 + mseg] = pack;
}

// ---------------- k3: y[n][c] = sum_m exp(S[n][m]) * gT[c][m] ---------------
// grid (64 n-blocks, 4 m-quarters, B). phi tile shared via LDS, pipelined.
__global__ __launch_bounds__(256, 4) void k3_attn(
    const unsigned short* __restrict__ thetaB,
    const unsigned short* __restrict__ phiTB,
    const unsigned short* __restrict__ gTB,
    unsigned short* __restrict__ Y)
{
    __shared__ unsigned short Lphi[64 * 136];   // [m-local][k], 272B rows
    __shared__ unsigned short Pl[64][72];       // [n-local][m-local], 144B rows
    const int t = threadIdx.x;
    const int lane = t & 63, w = t >> 6;
    const int ln = lane & 15, quad = lane >> 4;
    const int rowS = t >> 4, colS = t & 15;     // staging coords (16 rows/pass)
    const int n0 = blockIdx.x * 64, q = blockIdx.y, b = blockIdx.z;
    const unsigned short* th = thetaB + (size_t)b * NN_ * CB;
    const unsigned short* ph = phiTB + (size_t)b * NN_ * CB;
    const unsigned short* gT = gTB + (size_t)b * CB * HWD;

    // persistent theta A-frags (this wave's 16 n-rows)
    v8s ath[4];
    #pragma unroll
    for (int kt = 0; kt < 4; kt++)
        ath[kt] = *(const v8s*)&th[(size_t)(n0 + w * 16 + ln) * CB + kt * 32 + quad * 8];

    const int mBeg = q * 1024, mEnd = mBeg + 1024;
    // stage first phi tile
    #pragma unroll
    for (int pass = 0; pass < 4; pass++) {
        v8s v = *(const v8s*)&ph[(size_t)(mBeg + pass * 16 + rowS) * CB + colS * 8];
        *(v8s*)&Lphi[(pass * 16 + rowS) * 136 + colS * 8] = v;
    }
    __syncthreads();

    v4f yacc[2][4] = {};   // [ct: c-16-tile][nt: n-16-tile]
    for (int m0 = mBeg; m0 < mEnd; m0 += 64) {
        int mN = (m0 + 64 < mEnd) ? m0 + 64 : mBeg;   // clamp: harmless reload
        // prefetch next phi tile into regs (consumed after barrierA)
        v8s preg[4];
        #pragma unroll
        for (int pass = 0; pass < 4; pass++)
            preg[pass] = *(const v8s*)&ph[(size_t)(mN + pass * 16 + rowS) * CB + colS * 8];
        // prefetch gT frags for this iter (consumed in PV after barrier)
        v8s gfrag[2][2];
        #pragma unroll
        for (int ct = 0; ct < 2; ct++)
            #pragma unroll
            for (int kt2 = 0; kt2 < 2; kt2++)
                gfrag[ct][kt2] = *(const v8s*)&gT[(size_t)(w * 32 + ct * 16 + ln) * HWD + m0 + kt2 * 32 + quad * 8];
        // S phase from LDS phi
        v4f s[4] = {};
        #pragma unroll
        for (int mt = 0; mt < 4; mt++)
            #pragma unroll
            for (int kt = 0; kt < 4; kt++) {
                v8s bphi = *(const v8s*)&Lphi[(mt * 16 + ln) * 136 + kt * 32 + quad * 8];
                s[mt] = MFMA16(ath[kt], bphi, s[mt]);
            }
        float pv[4][4];
        #pragma unroll
        for (int mt = 0; mt < 4; mt++)
            #pragma unroll
            for (int r = 0; r < 4; r++)
                pv[mt][r] = __expf(s[mt][r]);
        __syncthreads();   // barrierA: all S reads + prior PV reads complete
        #pragma unroll
        for (int mt = 0; mt < 4; mt++)
            #pragma unroll
            for (int r = 0; r < 4; r++)
                Pl[w * 16 + quad * 4 + r][mt * 16 + ln] = f2bf(pv[mt][r]);
        #pragma unroll
        for (int pass = 0; pass < 4; pass++)
            *(v8s*)&Lphi[(pass * 16 + rowS) * 136 + colS * 8] = preg[pass];
        __syncthreads();   // barrierB: Pl + next phi tile visible
        // PV phase
        #pragma unroll
        for (int ct = 0; ct < 2; ct++)
            #pragma unroll
            for (int kt2 = 0; kt2 < 2; kt2++)
                #pragma unroll
                for (int nt = 0; nt < 4; nt++) {
                    v8s ap = *(const v8s*)&Pl[nt * 16 + ln][kt2 * 32 + quad * 8];
                    yacc[ct][nt] = MFMA16(ap, gfrag[ct][kt2], yacc[ct][nt]);
                }
    }
    unsigned short* yp = Y + U_Y - U_Y /*keep base*/ + ((size_t)q * NBATCH + b) * CB * HWD;
    #pragma unroll
    for (int ct = 0; ct < 2; ct++)
        #pragma unroll
        for (int nt = 0; nt < 4; nt++)
            #pragma unroll
            for (int r = 0; r < 4; r++)
                yp[(size_t)(n0 + nt * 16 + quad * 4 + r) * CB + w * 32 + ct * 16 + ln] =
                    f2bf(yacc[ct][nt][r]);
}

// ---------------- k4: out = Ww @ (sum of 4 bf16 Y partials) + Wb + x --------
__global__ __launch_bounds__(256) void k4_outconv(
    const float* __restrict__ x, const float* __restrict__ Ww,
    const float* __restrict__ Wb, const unsigned short* __restrict__ Ybuf,
    float* __restrict__ out)
{
    __shared__ float As[64 * 68];
    __shared__ float Bs[64 * 68];
    const int t = threadIdx.x, tx = t & 15, ty = t >> 4;
    const int hw0 = blockIdx.x * 64;
    const int o0  = blockIdx.y * 64;
    const int b   = blockIdx.z;

    float acc[4][4] = {};
    for (int kh = 0; kh < 2; kh++) {
        #pragma unroll
        for (int i = 0; i < 4; i++) {
            int flat4 = i * 256 + t;
            int row = flat4 >> 4, k4 = flat4 & 15;
            float4 f = *(const float4*)&Ww[(size_t)(o0 + row) * CB + kh * 64 + k4 * 4];
            As[(k4 * 4 + 0) * 68 + row] = f.x;
            As[(k4 * 4 + 1) * 68 + row] = f.y;
            As[(k4 * 4 + 2) * 68 + row] = f.z;
            As[(k4 * 4 + 3) * 68 + row] = f.w;
        }
        #pragma unroll
        for (int i = 0; i < 4; i++) {
            int flat4 = i * 256 + t;
            int krow = flat4 >> 4, c4 = flat4 & 15;
            size_t fi = (size_t)(kh * 64 + krow) * HWD + hw0 + c4 * 4;   // y_conv flat
            float sum[4] = {0.f, 0.f, 0.f, 0.f};
            #pragma unroll
            for (int qq = 0; qq < 4; qq++) {
                const unsigned short* yq = Ybuf + ((size_t)qq * NBATCH + b) * CB * HWD;
                ushort4 u = *(const ushort4*)&yq[fi];
                sum[0] += bf2f(u.x); sum[1] += bf2f(u.y);
                sum[2] += bf2f(u.z); sum[3] += bf2f(u.w);
            }
            *(float4*)&Bs[krow * 68 + c4 * 4] = make_float4(sum[0], sum[1], sum[2], sum[3]);
        }
        __syncthreads();
        #pragma unroll 8
        for (int k = 0; k < 64; k++) {
            float4 a4 = *(const float4*)&As[k * 68 + ty * 4];
            float4 b4 = *(const float4*)&Bs[k * 68 + tx * 4];
            float af[4] = {a4.x, a4.y, a4.z, a4.w};
            float bf[4] = {b4.x, b4.y, b4.z, b4.w};
            #pragma unroll
            for (int i = 0; i < 4; i++)
                #pragma unroll
                for (int j = 0; j < 4; j++)
                    acc[i][j] += af[i] * bf[j];
        }
        __syncthreads();
    }
    #pragma unroll
    for (int i = 0; i < 4; i++) {
        int o = o0 + ty * 4 + i;
        float bias = Wb[o];
        size_t idx = (size_t)b * CI * HWD + (size_t)o * HWD + hw0 + tx * 4;
        float4 xr = *(const float4*)&x[idx];
        float4 v;
        v.x = acc[i][0] + bias + xr.x;
        v.y = acc[i][1] + bias + xr.y;
        v.z = acc[i][2] + bias + xr.z;
        v.w = acc[i][3] + bias + xr.w;
        *(float4*)&out[idx] = v;
    }
}

extern "C" void kernel_launch(void* const* d_in, const int* in_sizes, int n_in,
                              void* d_out, int out_size, void* d_ws, size_t ws_size,
                              hipStream_t stream)
{
    const float* x  = (const float*)d_in[0];
    const float* tw = (const float*)d_in[1];
    const float* tb = (const float*)d_in[2];
    const float* pw = (const float*)d_in[3];
    const float* pb = (const float*)d_in[4];
    const float* gw = (const float*)d_in[5];
    const float* gb = (const float*)d_in[6];
    const float* Ww = (const float*)d_in[7];
    const float* Wb = (const float*)d_in[8];
    unsigned short* wsu = (unsigned short*)d_ws;
    float* wsf = (float*)d_ws;
    unsigned short* thetaB = wsu + U_THETA;
    unsigned short* phiTB  = wsu + U_PHIT;
    unsigned short* gB     = wsu + U_G;
    unsigned short* gTB    = wsu + U_GT;
    unsigned short* Ybuf   = wsu + U_Y;
    float* Dbuf = wsf + F_D;
    float* out = (float*)d_out;
    dim3 blk(256, 1, 1);
    hipLaunchKernelGGL(k1_conv_tpg, dim3(64, 6, NBATCH), blk, 0, stream,
                       x, tw, tb, pw, pb, gw, gb, thetaB, phiTB, gB);
    hipLaunchKernelGGL(k2_colsum, dim3(64, 4, NBATCH), blk, 0, stream,
                       thetaB, phiTB, Dbuf);
    hipLaunchKernelGGL(k1b_transpose_scale_g, dim3(128, 2, NBATCH), blk, 0, stream,
                       gB, Dbuf, gTB);
    hipLaunchKernelGGL(k3_attn, dim3(64, 4, NBATCH), blk, 0, stream,
                       thetaB, phiTB, gTB, Ybuf);
    hipLaunchKernelGGL(k4_outconv, dim3(64, 4, NBATCH), blk, 0, stream,
                       x, Ww, Wb, Ybuf, out);
}

// Round 5
// 214.967 us; speedup vs baseline: 4.5223x; 1.1507x over previous
//
#include <hip/hip_runtime.h>
#include <math.h>

// NonLocalBlock: B=4, C=256, Cb=128, H=W=64, N=HW=4096.
// Round 5: MFMA-ize k1 and k4 (round-4 counters: k1 fp32 GEMM 73us, MfmaUtil=0).
//   k0 : x -> xT[b][hw][cin] bf16 (LDS transpose); k0w: weights -> bf16
//   k1 : tpg = Wcat(384x256) @ x via bf16 MFMA; theta/g plain bf16, phiT via LDS
//   k2 : D[m] = sum_n exp(S[n][m]) via MFMA (unchanged)
//   k1b: gT[c][m] = gflat[m*128+c] / D[m]   (unchanged)
//   k3 : y[n][c] = sum_m exp(S[n][m]) * gT[c][m], bf16 partial-Y x4 (unchanged)
//   k4 : out = Ww @ (sum Y partials) + Wb + x via bf16 MFMA (Y tile LDS-transposed)
// ws: theta/phiT/g/gT 2M ushorts each + Y 8M (xT aliases Y: dead before k3)
//     + wcat/ww 131K ushorts + D 256KB  = ~32.5 MB.

constexpr int CI = 256;
constexpr int CB = 128;
constexpr int HWD = 4096;
constexpr int NBATCH = 4;
constexpr int NN_ = 4096;
constexpr size_t U1 = (size_t)NBATCH * NN_ * CB;            // 2,097,152
constexpr size_t U_THETA = 0;
constexpr size_t U_PHIT  = U1;
constexpr size_t U_G     = 2 * U1;
constexpr size_t U_GT    = 3 * U1;
constexpr size_t U_Y     = 4 * U1;                          // 4 quarters (4*U1)
constexpr size_t U_XT    = 4 * U1;                          // ALIAS: dead before k3 writes Y
constexpr size_t U_WCAT  = 8 * U1;                          // 384*256 = 98304
constexpr size_t U_WW    = 8 * U1 + 98304;                  // 256*128 = 32768
constexpr size_t F_D     = (8 * U1 + 131072) / 2;           // float units

typedef short v8s __attribute__((ext_vector_type(8)));
typedef unsigned short u8s __attribute__((ext_vector_type(8)));
typedef float v4f __attribute__((ext_vector_type(4)));
#define MFMA16(a, b, c) __builtin_amdgcn_mfma_f32_16x16x32_bf16(a, b, c, 0, 0, 0)

__device__ __forceinline__ unsigned short f2bf(float f) {
    union { float f; unsigned u; } v; v.f = f;
    unsigned r = v.u + 0x7fff + ((v.u >> 16) & 1);
    return (unsigned short)(r >> 16);
}
__device__ __forceinline__ float bf2f(unsigned short s) {
    union { unsigned u; float f; } v; v.u = (unsigned)s << 16;
    return v.f;
}

// ---------------- k0: xT[b][hw][cin] = bf16(x[b][cin][hw]) ------------------
__global__ __launch_bounds__(256) void k0_xpose(
    const float* __restrict__ x, unsigned short* __restrict__ xT)
{
    __shared__ unsigned short T[64 * 72];
    const int t = threadIdx.x;
    const int hw0 = blockIdx.x * 64, c0 = blockIdx.y * 64, b = blockIdx.z;
    const float* xb = x + (size_t)b * CI * HWD;
    const int rr = t >> 4, cc = t & 15;
    #pragma unroll
    for (int pass = 0; pass < 4; pass++) {
        float4 f = *(const float4*)&xb[(size_t)(c0 + pass * 16 + rr) * HWD + hw0 + cc * 4];
        T[(cc * 4 + 0) * 72 + pass * 16 + rr] = f2bf(f.x);
        T[(cc * 4 + 1) * 72 + pass * 16 + rr] = f2bf(f.y);
        T[(cc * 4 + 2) * 72 + pass * 16 + rr] = f2bf(f.z);
        T[(cc * 4 + 3) * 72 + pass * 16 + rr] = f2bf(f.w);
    }
    __syncthreads();
    const int row = t >> 2, cs = (t & 3) * 16;
    unsigned short* dst = xT + (size_t)b * NN_ * CI;
    #pragma unroll
    for (int h = 0; h < 2; h++)
        *(u8s*)&dst[(size_t)(hw0 + row) * CI + c0 + cs + h * 8] =
            *(const u8s*)&T[row * 72 + cs + h * 8];
}

// ---------------- k0w: weights -> bf16 (wcat 384x256 rows = theta/phi/g; ww) -
__global__ __launch_bounds__(256) void k0_weights(
    const float* __restrict__ tw, const float* __restrict__ pw,
    const float* __restrict__ gw, const float* __restrict__ Ww,
    unsigned short* __restrict__ wcat, unsigned short* __restrict__ wwB)
{
    int e = (blockIdx.x * 256 + threadIdx.x) * 4;   // 131072 total
    const float* src; unsigned short* dst;
    if (e < 32768)       { src = tw + e;          dst = wcat + e; }
    else if (e < 65536)  { src = pw + (e - 32768); dst = wcat + e; }
    else if (e < 98304)  { src = gw + (e - 65536); dst = wcat + e; }
    else                 { src = Ww + (e - 98304); dst = wwB + (e - 98304); }
    float4 f = *(const float4*)src;
    ushort4 u;
    u.x = f2bf(f.x); u.y = f2bf(f.y); u.z = f2bf(f.z); u.w = f2bf(f.w);
    *(ushort4*)dst = u;
}

// ---------------- k1: tpg = Wcat @ x via bf16 MFMA --------------------------
// grid (64 hw-tiles, 6 j-tiles, B)
__global__ __launch_bounds__(256, 2) void k1_mfma(
    const unsigned short* __restrict__ xT, const unsigned short* __restrict__ wcat,
    const float* __restrict__ tb, const float* __restrict__ pb,
    const float* __restrict__ gb,
    unsigned short* __restrict__ thetaB, unsigned short* __restrict__ phiTB,
    unsigned short* __restrict__ gB)
{
    __shared__ unsigned short T[64 * 72];
    const int t = threadIdx.x;
    const int lane = t & 63, w = t >> 6;
    const int ln = lane & 15, quad = lane >> 4;
    const int hw0 = blockIdx.x * 64, j0 = blockIdx.y * 64, b = blockIdx.z;
    const int matId = j0 >> 7, jl0 = j0 & 127;
    const float* bvec = (matId == 0) ? tb : (matId == 1) ? pb : gb;
    const unsigned short* xb = xT + (size_t)b * NN_ * CI;

    v8s aw[8];
    #pragma unroll
    for (int kt = 0; kt < 8; kt++)
        aw[kt] = *(const v8s*)&wcat[(size_t)(j0 + w * 16 + ln) * CI + kt * 32 + quad * 8];

    v4f s[4] = {};
    v8s bx[4], bxn[4];
    #pragma unroll
    for (int mt = 0; mt < 4; mt++)
        bx[mt] = *(const v8s*)&xb[(size_t)(hw0 + mt * 16 + ln) * CI + quad * 8];
    #pragma unroll
    for (int kt = 0; kt < 8; kt++) {
        if (kt < 7) {
            #pragma unroll
            for (int mt = 0; mt < 4; mt++)
                bxn[mt] = *(const v8s*)&xb[(size_t)(hw0 + mt * 16 + ln) * CI + (kt + 1) * 32 + quad * 8];
        }
        #pragma unroll
        for (int mt = 0; mt < 4; mt++)
            s[mt] = MFMA16(aw[kt], bx[mt], s[mt]);
        #pragma unroll
        for (int mt = 0; mt < 4; mt++) bx[mt] = bxn[mt];
    }

    float bias[4];
    #pragma unroll
    for (int r = 0; r < 4; r++) bias[r] = bvec[jl0 + w * 16 + quad * 4 + r];

    if (matId != 1) {
        // theta/g: plain conv-layout flat store [cb][hw]
        unsigned short* dst = ((matId == 0) ? thetaB : gB) + (size_t)b * CB * HWD;
        #pragma unroll
        for (int mt = 0; mt < 4; mt++)
            #pragma unroll
            for (int r = 0; r < 4; r++)
                dst[(size_t)(jl0 + w * 16 + quad * 4 + r) * HWD + hw0 + mt * 16 + ln] =
                    f2bf(s[mt][r] + bias[r]);
    } else {
        // phi: LDS transpose -> phiT[hw][cb] coalesced store
        #pragma unroll
        for (int mt = 0; mt < 4; mt++) {
            ushort4 pk;
            pk.x = f2bf(s[mt][0] + bias[0]);
            pk.y = f2bf(s[mt][1] + bias[1]);
            pk.z = f2bf(s[mt][2] + bias[2]);
            pk.w = f2bf(s[mt][3] + bias[3]);
            *(ushort4*)&T[(mt * 16 + ln) * 72 + w * 16 + quad * 4] = pk;
        }
        __syncthreads();
        unsigned short* dst = phiTB + (size_t)b * NN_ * CB;
        const int row = t >> 2, cs = (t & 3) * 16;
        #pragma unroll
        for (int h = 0; h < 2; h++)
            *(u8s*)&dst[(size_t)(hw0 + row) * CB + jl0 + cs + h * 8] =
                *(const u8s*)&T[row * 72 + cs + h * 8];
    }
}

// ---------------- k2: D[m] = sum_n exp(S[n][m]), prefetched MFMA ------------
__global__ __launch_bounds__(256, 4) void k2_colsum(
    const unsigned short* __restrict__ thetaB,
    const unsigned short* __restrict__ phiTB,
    float* __restrict__ Dout)
{
    __shared__ float part[4][64];
    const int t = threadIdx.x;
    const int lane = t & 63, w = t >> 6;
    const int ln = lane & 15, quad = lane >> 4;
    const int m0 = blockIdx.x * 64, q = blockIdx.y, b = blockIdx.z;
    const unsigned short* th = thetaB + (size_t)b * NN_ * CB;
    const unsigned short* ph = phiTB + (size_t)b * NN_ * CB;

    v8s bf[4][4];
    #pragma unroll
    for (int mt = 0; mt < 4; mt++)
        #pragma unroll
        for (int kt = 0; kt < 4; kt++)
            bf[mt][kt] = *(const v8s*)&ph[(size_t)(m0 + mt * 16 + ln) * CB + kt * 32 + quad * 8];

    float dsum[4] = {0.f, 0.f, 0.f, 0.f};
    const int nBeg = q * 1024 + w * 16, nEnd = q * 1024 + 1024;
    v8s af[4], afn[4];
    #pragma unroll
    for (int kt = 0; kt < 4; kt++)
        af[kt] = *(const v8s*)&th[(size_t)(nBeg + ln) * CB + kt * 32 + quad * 8];
    for (int n0 = nBeg; n0 < nEnd; n0 += 64) {
        int nn = (n0 + 64 < nEnd) ? n0 + 64 : nBeg;
        #pragma unroll
        for (int kt = 0; kt < 4; kt++)
            afn[kt] = *(const v8s*)&th[(size_t)(nn + ln) * CB + kt * 32 + quad * 8];
        v4f s[4] = {};
        #pragma unroll
        for (int mt = 0; mt < 4; mt++)
            #pragma unroll
            for (int kt = 0; kt < 4; kt++)
                s[mt] = MFMA16(af[kt], bf[mt][kt], s[mt]);
        #pragma unroll
        for (int mt = 0; mt < 4; mt++)
            #pragma unroll
            for (int r = 0; r < 4; r++)
                dsum[mt] += __expf(s[mt][r]);
        #pragma unroll
        for (int kt = 0; kt < 4; kt++) af[kt] = afn[kt];
    }
    #pragma unroll
    for (int mt = 0; mt < 4; mt++) {
        float v = dsum[mt];
        v += __shfl_xor(v, 16);
        v += __shfl_xor(v, 32);
        dsum[mt] = v;
    }
    if (quad == 0) {
        #pragma unroll
        for (int mt = 0; mt < 4; mt++) part[w][mt * 16 + ln] = dsum[mt];
    }
    __syncthreads();
    if (t < 64) {
        float v = part[0][t] + part[1][t] + part[2][t] + part[3][t];
        Dout[((size_t)q * NBATCH + b) * NN_ + m0 + t] = v;
    }
}

// ---------------- k1b: gT[c][m] = gflat[m*128+c] / D[m] ---------------------
__global__ __launch_bounds__(256) void k1b_transpose_scale_g(
    const unsigned short* __restrict__ gB, const float* __restrict__ D,
    unsigned short* __restrict__ gTB)
{
    const int t = threadIdx.x;
    const int m0 = blockIdx.x * 32;
    const int c0 = blockIdx.y * 64;
    const int b  = blockIdx.z;
    const unsigned short* src = gB + (size_t)b * CB * HWD;
    unsigned short* dst = gTB + (size_t)b * CB * HWD;
    const int c = c0 + (t & 63);
    const int mseg = (t >> 6) * 8;
    u8s pack;
    #pragma unroll
    for (int j = 0; j < 8; j++) {
        int m = m0 + mseg + j;
        float d = D[((size_t)0 * NBATCH + b) * NN_ + m]
                + D[((size_t)1 * NBATCH + b) * NN_ + m]
                + D[((size_t)2 * NBATCH + b) * NN_ + m]
                + D[((size_t)3 * NBATCH + b) * NN_ + m];
        float r = 1.0f / d;
        pack[j] = f2bf(bf2f(src[(size_t)m * CB + c]) * r);
    }
    *(u8s*)&dst[(size_t)c * HWD + m0 + mseg] = pack;
}

// ---------------- k3: y[n][c] = sum_m exp(S[n][m]) * gT[c][m] ---------------
__global__ __launch_bounds__(256, 4) void k3_attn(
    const unsigned short* __restrict__ thetaB,
    const unsigned short* __restrict__ phiTB,
    const unsigned short* __restrict__ gTB,
    unsigned short* __restrict__ Y)
{
    __shared__ unsigned short Lphi[64 * 136];
    __shared__ unsigned short Pl[64][72];
    const int t = threadIdx.x;
    const int lane = t & 63, w = t >> 6;
    const int ln = lane & 15, quad = lane >> 4;
    const int rowS = t >> 4, colS = t & 15;
    const int n0 = blockIdx.x * 64, q = blockIdx.y, b = blockIdx.z;
    const unsigned short* th = thetaB + (size_t)b * NN_ * CB;
    const unsigned short* ph = phiTB + (size_t)b * NN_ * CB;
    const unsigned short* gT = gTB + (size_t)b * CB * HWD;

    v8s ath[4];
    #pragma unroll
    for (int kt = 0; kt < 4; kt++)
        ath[kt] = *(const v8s*)&th[(size_t)(n0 + w * 16 + ln) * CB + kt * 32 + quad * 8];

    const int mBeg = q * 1024, mEnd = mBeg + 1024;
    #pragma unroll
    for (int pass = 0; pass < 4; pass++) {
        v8s v = *(const v8s*)&ph[(size_t)(mBeg + pass * 16 + rowS) * CB + colS * 8];
        *(v8s*)&Lphi[(pass * 16 + rowS) * 136 + colS * 8] = v;
    }
    __syncthreads();

    v4f yacc[2][4] = {};
    for (int m0 = mBeg; m0 < mEnd; m0 += 64) {
        int mN = (m0 + 64 < mEnd) ? m0 + 64 : mBeg;
        v8s preg[4];
        #pragma unroll
        for (int pass = 0; pass < 4; pass++)
            preg[pass] = *(const v8s*)&ph[(size_t)(mN + pass * 16 + rowS) * CB + colS * 8];
        v8s gfrag[2][2];
        #pragma unroll
        for (int ct = 0; ct < 2; ct++)
            #pragma unroll
            for (int kt2 = 0; kt2 < 2; kt2++)
                gfrag[ct][kt2] = *(const v8s*)&gT[(size_t)(w * 32 + ct * 16 + ln) * HWD + m0 + kt2 * 32 + quad * 8];
        v4f s[4] = {};
        #pragma unroll
        for (int mt = 0; mt < 4; mt++)
            #pragma unroll
            for (int kt = 0; kt < 4; kt++) {
                v8s bphi = *(const v8s*)&Lphi[(mt * 16 + ln) * 136 + kt * 32 + quad * 8];
                s[mt] = MFMA16(ath[kt], bphi, s[mt]);
            }
        float pv[4][4];
        #pragma unroll
        for (int mt = 0; mt < 4; mt++)
            #pragma unroll
            for (int r = 0; r < 4; r++)
                pv[mt][r] = __expf(s[mt][r]);
        __syncthreads();
        #pragma unroll
        for (int mt = 0; mt < 4; mt++)
            #pragma unroll
            for (int r = 0; r < 4; r++)
                Pl[w * 16 + quad * 4 + r][mt * 16 + ln] = f2bf(pv[mt][r]);
        #pragma unroll
        for (int pass = 0; pass < 4; pass++)
            *(v8s*)&Lphi[(pass * 16 + rowS) * 136 + colS * 8] = preg[pass];
        __syncthreads();
        #pragma unroll
        for (int ct = 0; ct < 2; ct++)
            #pragma unroll
            for (int kt2 = 0; kt2 < 2; kt2++)
                #pragma unroll
                for (int nt = 0; nt < 4; nt++) {
                    v8s ap = *(const v8s*)&Pl[nt * 16 + ln][kt2 * 32 + quad * 8];
                    yacc[ct][nt] = MFMA16(ap, gfrag[ct][kt2], yacc[ct][nt]);
                }
    }
    unsigned short* yp = Y + ((size_t)q * NBATCH + b) * CB * HWD;
    #pragma unroll
    for (int ct = 0; ct < 2; ct++)
        #pragma unroll
        for (int nt = 0; nt < 4; nt++)
            #pragma unroll
            for (int r = 0; r < 4; r++)
                yp[(size_t)(n0 + nt * 16 + quad * 4 + r) * CB + w * 32 + ct * 16 + ln] =
                    f2bf(yacc[ct][nt][r]);
}

// ---------------- k4: out = Ww @ (sum Y partials) + Wb + x via MFMA ---------
// grid (64 hw-tiles, 2 o-halves, B)
__global__ __launch_bounds__(256, 2) void k4_mfma(
    const float* __restrict__ x, const unsigned short* __restrict__ wwB,
    const float* __restrict__ Wb, const unsigned short* __restrict__ Ybuf,
    float* __restrict__ out)
{
    __shared__ unsigned short Yt[64 * 136];
    const int t = threadIdx.x;
    const int lane = t & 63, w = t >> 6;
    const int ln = lane & 15, quad = lane >> 4;
    const int hw0 = blockIdx.x * 64, o0 = blockIdx.y * 128, b = blockIdx.z;

    // stage summed yconv tile, transposed to [hw][cb]
    const int cb = t >> 1, seg = (t & 1) * 32;
    #pragma unroll
    for (int g8 = 0; g8 < 4; g8++) {
        float sum[8] = {};
        #pragma unroll
        for (int q = 0; q < 4; q++) {
            u8s u = *(const u8s*)&Ybuf[((size_t)q * NBATCH + b) * CB * HWD +
                                       (size_t)cb * HWD + hw0 + seg + g8 * 8];
            #pragma unroll
            for (int j = 0; j < 8; j++) sum[j] += bf2f(u[j]);
        }
        #pragma unroll
        for (int j = 0; j < 8; j++)
            Yt[(seg + g8 * 8 + j) * 136 + cb] = f2bf(sum[j]);
    }
    __syncthreads();

    v8s aw[2][4];
    #pragma unroll
    for (int os = 0; os < 2; os++)
        #pragma unroll
        for (int kt = 0; kt < 4; kt++)
            aw[os][kt] = *(const v8s*)&wwB[(size_t)(o0 + w * 32 + os * 16 + ln) * CB + kt * 32 + quad * 8];

    v4f s[2][4] = {};
    #pragma unroll
    for (int kt = 0; kt < 4; kt++) {
        v8s by[4];
        #pragma unroll
        for (int mt = 0; mt < 4; mt++)
            by[mt] = *(const v8s*)&Yt[(mt * 16 + ln) * 136 + kt * 32 + quad * 8];
        #pragma unroll
        for (int os = 0; os < 2; os++)
            #pragma unroll
            for (int mt = 0; mt < 4; mt++)
                s[os][mt] = MFMA16(aw[os][kt], by[mt], s[os][mt]);
    }
    float bias[2][4];
    #pragma unroll
    for (int os = 0; os < 2; os++)
        #pragma unroll
        for (int r = 0; r < 4; r++)
            bias[os][r] = Wb[o0 + w * 32 + os * 16 + quad * 4 + r];
    #pragma unroll
    for (int os = 0; os < 2; os++)
        #pragma unroll
        for (int mt = 0; mt < 4; mt++)
            #pragma unroll
            for (int r = 0; r < 4; r++) {
                int o = o0 + w * 32 + os * 16 + quad * 4 + r;
                size_t idx = (size_t)b * CI * HWD + (size_t)o * HWD + hw0 + mt * 16 + ln;
                out[idx] = s[os][mt][r] + bias[os][r] + x[idx];
            }
}

extern "C" void kernel_launch(void* const* d_in, const int* in_sizes, int n_in,
                              void* d_out, int out_size, void* d_ws, size_t ws_size,
                              hipStream_t stream)
{
    const float* x  = (const float*)d_in[0];
    const float* tw = (const float*)d_in[1];
    const float* tb = (const float*)d_in[2];
    const float* pw = (const float*)d_in[3];
    const float* pb = (const float*)d_in[4];
    const float* gw = (const float*)d_in[5];
    const float* gb = (const float*)d_in[6];
    const float* Ww = (const float*)d_in[7];
    const float* Wb = (const float*)d_in[8];
    unsigned short* wsu = (unsigned short*)d_ws;
    float* wsf = (float*)d_ws;
    unsigned short* thetaB = wsu + U_THETA;
    unsigned short* phiTB  = wsu + U_PHIT;
    unsigned short* gB     = wsu + U_G;
    unsigned short* gTB    = wsu + U_GT;
    unsigned short* Ybuf   = wsu + U_Y;
    unsigned short* xTB    = wsu + U_XT;     // aliases Ybuf (xT dead before k3)
    unsigned short* wcatB  = wsu + U_WCAT;
    unsigned short* wwB    = wsu + U_WW;
    float* Dbuf = wsf + F_D;
    float* out = (float*)d_out;
    dim3 blk(256, 1, 1);
    hipLaunchKernelGGL(k0_xpose, dim3(64, 4, NBATCH), blk, 0, stream, x, xTB);
    hipLaunchKernelGGL(k0_weights, dim3(128, 1, 1), blk, 0, stream,
                       tw, pw, gw, Ww, wcatB, wwB);
    hipLaunchKernelGGL(k1_mfma, dim3(64, 6, NBATCH), blk, 0, stream,
                       xTB, wcatB, tb, pb, gb, thetaB, phiTB, gB);
    hipLaunchKernelGGL(k2_colsum, dim3(64, 4, NBATCH), blk, 0, stream,
                       thetaB, phiTB, Dbuf);
    hipLaunchKernelGGL(k1b_transpose_scale_g, dim3(128, 2, NBATCH), blk, 0, stream,
                       gB, Dbuf, gTB);
    hipLaunchKernelGGL(k3_attn, dim3(64, 4, NBATCH), blk, 0, stream,
                       thetaB, phiTB, gTB, Ybuf);
    hipLaunchKernelGGL(k4_mfma, dim3(64, 2, NBATCH), blk, 0, stream,
                       x, wwB, Wb, Ybuf, out);
}

// Round 6
// 211.024 us; speedup vs baseline: 4.6068x; 1.0187x over previous
//
#include <hip/hip_runtime.h>
#include <math.h>

// NonLocalBlock: B=4, C=256, Cb=128, H=W=64, N=HW=4096.
// Round 6: 32x32x16 MFMA in k1/k3 (halves LDS bytes/FLOP; round-5 k3 was
// LDS-throughput-bound at MfmaUtil 24%), k1 LDS-stages xT, k1b coalesced.
//   k0 : x -> xT[b][hw][cin] bf16; k0w: weights -> bf16
//   k1 : tpg = Wcat(384x256) @ x, 32x32x16; xT tile in LDS; theta/g plain, phiT
//   k2 : D[m] = sum_n exp(S[n][m]) (16x16x32, reg-resident B)
//   k1b: gT[c][m] = gflat[m*128+c] / D[m]  (LDS tile transpose)
//   k3 : y[n][c] = sum_m exp(S[n][m]) * gT[c][m], 32x32x16 both phases
//   k4 : out = Ww @ (sum Y partials) + Wb + x (16x16x32)
constexpr int CI = 256;
constexpr int CB = 128;
constexpr int HWD = 4096;
constexpr int NBATCH = 4;
constexpr int NN_ = 4096;
constexpr size_t U1 = (size_t)NBATCH * NN_ * CB;            // 2,097,152
constexpr size_t U_THETA = 0;
constexpr size_t U_PHIT  = U1;
constexpr size_t U_G     = 2 * U1;
constexpr size_t U_GT    = 3 * U1;
constexpr size_t U_Y     = 4 * U1;                          // 4 quarters
constexpr size_t U_XT    = 4 * U1;                          // alias (xT dead before k3)
constexpr size_t U_WCAT  = 8 * U1;
constexpr size_t U_WW    = 8 * U1 + 98304;
constexpr size_t F_D     = (8 * U1 + 131072) / 2;

typedef short v8s __attribute__((ext_vector_type(8)));
typedef unsigned short u8s __attribute__((ext_vector_type(8)));
typedef float v4f __attribute__((ext_vector_type(4)));
typedef float v16f __attribute__((ext_vector_type(16)));
#define MFMA16(a, b, c) __builtin_amdgcn_mfma_f32_16x16x32_bf16(a, b, c, 0, 0, 0)
#define MFMA32(a, b, c) __builtin_amdgcn_mfma_f32_32x32x16_bf16(a, b, c, 0, 0, 0)

__device__ __forceinline__ unsigned short f2bf(float f) {
    union { float f; unsigned u; } v; v.f = f;
    unsigned r = v.u + 0x7fff + ((v.u >> 16) & 1);
    return (unsigned short)(r >> 16);
}
__device__ __forceinline__ float bf2f(unsigned short s) {
    union { unsigned u; float f; } v; v.u = (unsigned)s << 16;
    return v.f;
}

// ---------------- k0: xT[b][hw][cin] = bf16(x[b][cin][hw]) ------------------
__global__ __launch_bounds__(256) void k0_xpose(
    const float* __restrict__ x, unsigned short* __restrict__ xT)
{
    __shared__ unsigned short T[64 * 72];
    const int t = threadIdx.x;
    const int hw0 = blockIdx.x * 64, c0 = blockIdx.y * 64, b = blockIdx.z;
    const float* xb = x + (size_t)b * CI * HWD;
    const int rr = t >> 4, cc = t & 15;
    #pragma unroll
    for (int pass = 0; pass < 4; pass++) {
        float4 f = *(const float4*)&xb[(size_t)(c0 + pass * 16 + rr) * HWD + hw0 + cc * 4];
        T[(cc * 4 + 0) * 72 + pass * 16 + rr] = f2bf(f.x);
        T[(cc * 4 + 1) * 72 + pass * 16 + rr] = f2bf(f.y);
        T[(cc * 4 + 2) * 72 + pass * 16 + rr] = f2bf(f.z);
        T[(cc * 4 + 3) * 72 + pass * 16 + rr] = f2bf(f.w);
    }
    __syncthreads();
    const int row = t >> 2, cs = (t & 3) * 16;
    unsigned short* dst = xT + (size_t)b * NN_ * CI;
    #pragma unroll
    for (int h = 0; h < 2; h++)
        *(u8s*)&dst[(size_t)(hw0 + row) * CI + c0 + cs + h * 8] =
            *(const u8s*)&T[row * 72 + cs + h * 8];
}

// ---------------- k0w: weights -> bf16 --------------------------------------
__global__ __launch_bounds__(256) void k0_weights(
    const float* __restrict__ tw, const float* __restrict__ pw,
    const float* __restrict__ gw, const float* __restrict__ Ww,
    unsigned short* __restrict__ wcat, unsigned short* __restrict__ wwB)
{
    int e = (blockIdx.x * 256 + threadIdx.x) * 4;
    const float* src; unsigned short* dst;
    if (e < 32768)       { src = tw + e;          dst = wcat + e; }
    else if (e < 65536)  { src = pw + (e - 32768); dst = wcat + e; }
    else if (e < 98304)  { src = gw + (e - 65536); dst = wcat + e; }
    else                 { src = Ww + (e - 98304); dst = wwB + (e - 98304); }
    float4 f = *(const float4*)src;
    ushort4 u;
    u.x = f2bf(f.x); u.y = f2bf(f.y); u.z = f2bf(f.z); u.w = f2bf(f.w);
    *(ushort4*)dst = u;
}

// ---------------- k1: tpg = Wcat @ x, 32x32x16, xT tile staged in LDS -------
// grid (64 hw-tiles, 6 j-tiles, B); wave quadrants (qj = w>>1, qh = w&1)
__global__ __launch_bounds__(256, 4) void k1_mfma(
    const unsigned short* __restrict__ xT, const unsigned short* __restrict__ wcat,
    const float* __restrict__ tb, const float* __restrict__ pb,
    const float* __restrict__ gb,
    unsigned short* __restrict__ thetaB, unsigned short* __restrict__ phiTB,
    unsigned short* __restrict__ gB)
{
    __shared__ unsigned short LdsX[64 * 268];   // [hw][cin], 536B stride
    unsigned short* T = LdsX;                   // alias for phi transpose
    const int t = threadIdx.x;
    const int lane = t & 63, w = t >> 6;
    const int l31 = lane & 31, lh = lane >> 5;
    const int qj = w >> 1, qh = w & 1;
    const int hw0 = blockIdx.x * 64, j0 = blockIdx.y * 64, b = blockIdx.z;
    const int matId = j0 >> 7, jl0 = j0 & 127;
    const float* bvec = (matId == 0) ? tb : (matId == 1) ? pb : gb;
    const unsigned short* xb = xT + (size_t)b * NN_ * CI;

    {   // stage xT tile: 64 hw x 256 cin
        const int row = t >> 2, seg = t & 3;
        #pragma unroll
        for (int c8 = 0; c8 < 8; c8++)
            *(u8s*)&LdsX[row * 268 + seg * 64 + c8 * 8] =
                *(const u8s*)&xb[(size_t)(hw0 + row) * CI + seg * 64 + c8 * 8];
    }
    __syncthreads();

    v16f s = {};
    #pragma unroll
    for (int kt = 0; kt < 16; kt++) {
        v8s a = *(const v8s*)&wcat[(size_t)(j0 + qj * 32 + l31) * CI + kt * 16 + lh * 8];
        v8s bx = *(const v8s*)&LdsX[(qh * 32 + l31) * 268 + kt * 16 + lh * 8];
        s = MFMA32(a, bx, s);
    }

    if (matId != 1) {
        unsigned short* dst = ((matId == 0) ? thetaB : gB) + (size_t)b * CB * HWD;
        #pragma unroll
        for (int reg = 0; reg < 16; reg++) {
            int row = (reg & 3) + 8 * (reg >> 2) + 4 * lh;   // j-local in quadrant
            int cb = jl0 + qj * 32 + row;
            dst[(size_t)cb * HWD + hw0 + qh * 32 + l31] = f2bf(s[reg] + bvec[cb]);
        }
    } else {
        __syncthreads();   // all LdsX reads done before overwrite
        #pragma unroll
        for (int reg = 0; reg < 16; reg++) {
            int row = (reg & 3) + 8 * (reg >> 2) + 4 * lh;
            T[(qh * 32 + l31) * 76 + qj * 32 + row] =
                f2bf(s[reg] + bvec[jl0 + qj * 32 + row]);
        }
        __syncthreads();
        unsigned short* dst = phiTB + (size_t)b * NN_ * CB;
        const int row = t >> 2, cs = (t & 3) * 16;
        #pragma unroll
        for (int h = 0; h < 2; h++)
            *(u8s*)&dst[(size_t)(hw0 + row) * CB + jl0 + cs + h * 8] =
                *(const u8s*)&T[row * 76 + cs + h * 8];
    }
}

// ---------------- k2: D[m] = sum_n exp(S[n][m]) -----------------------------
__global__ __launch_bounds__(256, 4) void k2_colsum(
    const unsigned short* __restrict__ thetaB,
    const unsigned short* __restrict__ phiTB,
    float* __restrict__ Dout)
{
    __shared__ float part[4][64];
    const int t = threadIdx.x;
    const int lane = t & 63, w = t >> 6;
    const int ln = lane & 15, quad = lane >> 4;
    const int m0 = blockIdx.x * 64, q = blockIdx.y, b = blockIdx.z;
    const unsigned short* th = thetaB + (size_t)b * NN_ * CB;
    const unsigned short* ph = phiTB + (size_t)b * NN_ * CB;

    v8s bf[4][4];
    #pragma unroll
    for (int mt = 0; mt < 4; mt++)
        #pragma unroll
        for (int kt = 0; kt < 4; kt++)
            bf[mt][kt] = *(const v8s*)&ph[(size_t)(m0 + mt * 16 + ln) * CB + kt * 32 + quad * 8];

    float dsum[4] = {0.f, 0.f, 0.f, 0.f};
    const int nBeg = q * 1024 + w * 16, nEnd = q * 1024 + 1024;
    v8s af[4], afn[4];
    #pragma unroll
    for (int kt = 0; kt < 4; kt++)
        af[kt] = *(const v8s*)&th[(size_t)(nBeg + ln) * CB + kt * 32 + quad * 8];
    for (int n0 = nBeg; n0 < nEnd; n0 += 64) {
        int nn = (n0 + 64 < nEnd) ? n0 + 64 : nBeg;
        #pragma unroll
        for (int kt = 0; kt < 4; kt++)
            afn[kt] = *(const v8s*)&th[(size_t)(nn + ln) * CB + kt * 32 + quad * 8];
        v4f s[4] = {};
        #pragma unroll
        for (int mt = 0; mt < 4; mt++)
            #pragma unroll
            for (int kt = 0; kt < 4; kt++)
                s[mt] = MFMA16(af[kt], bf[mt][kt], s[mt]);
        #pragma unroll
        for (int mt = 0; mt < 4; mt++)
            #pragma unroll
            for (int r = 0; r < 4; r++)
                dsum[mt] += __expf(s[mt][r]);
        #pragma unroll
        for (int kt = 0; kt < 4; kt++) af[kt] = afn[kt];
    }
    #pragma unroll
    for (int mt = 0; mt < 4; mt++) {
        float v = dsum[mt];
        v += __shfl_xor(v, 16);
        v += __shfl_xor(v, 32);
        dsum[mt] = v;
    }
    if (quad == 0) {
        #pragma unroll
        for (int mt = 0; mt < 4; mt++) part[w][mt * 16 + ln] = dsum[mt];
    }
    __syncthreads();
    if (t < 64) {
        float v = part[0][t] + part[1][t] + part[2][t] + part[3][t];
        Dout[((size_t)q * NBATCH + b) * NN_ + m0 + t] = v;
    }
}

// ---------------- k1b: gT[c][m] = F[m*128+c] / D[m], LDS transpose ----------
// grid (128 m-tiles of 32, 1, B)
__global__ __launch_bounds__(256) void k1b_transpose_scale_g(
    const unsigned short* __restrict__ gB, const float* __restrict__ D,
    unsigned short* __restrict__ gTB)
{
    __shared__ unsigned short T[128 * 36];   // [c][m-local]
    const int t = threadIdx.x;
    const int m0 = blockIdx.x * 32;
    const int b  = blockIdx.z;
    const unsigned short* F = gB + (size_t)b * CB * HWD;
    unsigned short* dst = gTB + (size_t)b * CB * HWD;
    const int mrow = t >> 3, cg = t & 7;
    {
        int m = m0 + mrow;
        float d = D[((size_t)0 * NBATCH + b) * NN_ + m]
                + D[((size_t)1 * NBATCH + b) * NN_ + m]
                + D[((size_t)2 * NBATCH + b) * NN_ + m]
                + D[((size_t)3 * NBATCH + b) * NN_ + m];
        float r = 1.0f / d;
        #pragma unroll
        for (int j8 = 0; j8 < 2; j8++) {
            int cbase = cg * 8 + j8 * 64;
            u8s u = *(const u8s*)&F[(size_t)m * CB + cbase];
            #pragma unroll
            for (int e = 0; e < 8; e++)
                T[(cbase + e) * 36 + mrow] = f2bf(bf2f(u[e]) * r);
        }
    }
    __syncthreads();
    const int c = t >> 1, mh = (t & 1) * 16;
    #pragma unroll
    for (int h8 = 0; h8 < 2; h8++)
        *(u8s*)&dst[(size_t)c * HWD + m0 + mh + h8 * 8] =
            *(const u8s*)&T[c * 36 + mh + h8 * 8];
}

// ---------------- k3: y[n][c] = sum_m exp(S[n][m]) * gT[c][m], 32x32x16 -----
// grid (64 n-blocks, 4 m-quarters, B). S: waves = (qn,qm) quadrants.
// PV: wave w covers c-strip w*32, both n 32-halves (bg shared across nt).
__global__ __launch_bounds__(256, 4) void k3_attn(
    const unsigned short* __restrict__ thetaB,
    const unsigned short* __restrict__ phiTB,
    const unsigned short* __restrict__ gTB,
    unsigned short* __restrict__ Y)
{
    __shared__ unsigned short Lphi[64 * 140];   // [m-local][k], 280B stride
    __shared__ unsigned short Pl[64 * 76];      // [n-local][m-local], 152B stride
    const int t = threadIdx.x;
    const int lane = t & 63, w = t >> 6;
    const int l31 = lane & 31, lh = lane >> 5;
    const int qn = w & 1, qm = w >> 1;
    const int rowS = t >> 4, colS = t & 15;
    const int n0 = blockIdx.x * 64, q = blockIdx.y, b = blockIdx.z;
    const unsigned short* th = thetaB + (size_t)b * NN_ * CB;
    const unsigned short* ph = phiTB + (size_t)b * NN_ * CB;
    const unsigned short* gT = gTB + (size_t)b * CB * HWD;

    // persistent theta A-frags: rows n0+qn*32+l31, k = 128 in 8 steps of 16
    v8s ath[8];
    #pragma unroll
    for (int kt = 0; kt < 8; kt++)
        ath[kt] = *(const v8s*)&th[(size_t)(n0 + qn * 32 + l31) * CB + kt * 16 + lh * 8];

    const int mBeg = q * 1024, mEnd = mBeg + 1024;
    #pragma unroll
    for (int pass = 0; pass < 4; pass++)
        *(v8s*)&Lphi[(pass * 16 + rowS) * 140 + colS * 8] =
            *(const v8s*)&ph[(size_t)(mBeg + pass * 16 + rowS) * CB + colS * 8];
    __syncthreads();

    v16f yacc[2] = {};   // nt = 0,1 (n halves); wave's c-strip = w*32
    for (int m0 = mBeg; m0 < mEnd; m0 += 64) {
        int mN = (m0 + 64 < mEnd) ? m0 + 64 : mBeg;
        v8s preg[4];
        #pragma unroll
        for (int pass = 0; pass < 4; pass++)
            preg[pass] = *(const v8s*)&ph[(size_t)(mN + pass * 16 + rowS) * CB + colS * 8];
        // S phase: one 32x32 quadrant per wave
        v16f s = {};
        #pragma unroll
        for (int kt = 0; kt < 8; kt++) {
            v8s bphi = *(const v8s*)&Lphi[(qm * 32 + l31) * 140 + kt * 16 + lh * 8];
            s = MFMA32(ath[kt], bphi, s);
        }
        __syncthreads();   // prior PV reads of Pl done; S reads of Lphi done
        #pragma unroll
        for (int reg = 0; reg < 16; reg++) {
            int row = qn * 32 + (reg & 3) + 8 * (reg >> 2) + 4 * lh;   // n-local
            Pl[row * 76 + qm * 32 + l31] = f2bf(__expf(s[reg]));
        }
        #pragma unroll
        for (int pass = 0; pass < 4; pass++)
            *(v8s*)&Lphi[(pass * 16 + rowS) * 140 + colS * 8] = preg[pass];
        __syncthreads();
        // PV phase
        #pragma unroll
        for (int kstep = 0; kstep < 4; kstep++) {
            v8s bg = *(const v8s*)&gT[(size_t)(w * 32 + l31) * HWD + m0 + kstep * 16 + lh * 8];
            #pragma unroll
            for (int nt = 0; nt < 2; nt++) {
                v8s ap = *(const v8s*)&Pl[(nt * 32 + l31) * 76 + kstep * 16 + lh * 8];
                yacc[nt] = MFMA32(ap, bg, yacc[nt]);
            }
        }
    }
    unsigned short* yp = Y + ((size_t)q * NBATCH + b) * CB * HWD;
    #pragma unroll
    for (int nt = 0; nt < 2; nt++)
        #pragma unroll
        for (int reg = 0; reg < 16; reg++) {
            int row = (reg & 3) + 8 * (reg >> 2) + 4 * lh;
            yp[(size_t)(n0 + nt * 32 + row) * CB + w * 32 + l31] = f2bf(yacc[nt][reg]);
        }
}

// ---------------- k4: out = Ww @ (sum Y partials) + Wb + x ------------------
__global__ __launch_bounds__(256, 2) void k4_mfma(
    const float* __restrict__ x, const unsigned short* __restrict__ wwB,
    const float* __restrict__ Wb, const unsigned short* __restrict__ Ybuf,
    float* __restrict__ out)
{
    __shared__ unsigned short Yt[64 * 136];
    const int t = threadIdx.x;
    const int lane = t & 63, w = t >> 6;
    const int ln = lane & 15, quad = lane >> 4;
    const int hw0 = blockIdx.x * 64, o0 = blockIdx.y * 128, b = blockIdx.z;

    const int cb = t >> 1, seg = (t & 1) * 32;
    #pragma unroll
    for (int g8 = 0; g8 < 4; g8++) {
        float sum[8] = {};
        #pragma unroll
        for (int q = 0; q < 4; q++) {
            u8s u = *(const u8s*)&Ybuf[((size_t)q * NBATCH + b) * CB * HWD +
                                       (size_t)cb * HWD + hw0 + seg + g8 * 8];
            #pragma unroll
            for (int j = 0; j < 8; j++) sum[j] += bf2f(u[j]);
        }
        #pragma unroll
        for (int j = 0; j < 8; j++)
            Yt[(seg + g8 * 8 + j) * 136 + cb] = f2bf(sum[j]);
    }
    __syncthreads();

    v8s aw[2][4];
    #pragma unroll
    for (int os = 0; os < 2; os++)
        #pragma unroll
        for (int kt = 0; kt < 4; kt++)
            aw[os][kt] = *(const v8s*)&wwB[(size_t)(o0 + w * 32 + os * 16 + ln) * CB + kt * 32 + quad * 8];

    v4f s[2][4] = {};
    #pragma unroll
    for (int kt = 0; kt < 4; kt++) {
        v8s by[4];
        #pragma unroll
        for (int mt = 0; mt < 4; mt++)
            by[mt] = *(const v8s*)&Yt[(mt * 16 + ln) * 136 + kt * 32 + quad * 8];
        #pragma unroll
        for (int os = 0; os < 2; os++)
            #pragma unroll
            for (int mt = 0; mt < 4; mt++)
                s[os][mt] = MFMA16(aw[os][kt], by[mt], s[os][mt]);
    }
    #pragma unroll
    for (int os = 0; os < 2; os++)
        #pragma unroll
        for (int mt = 0; mt < 4; mt++)
            #pragma unroll
            for (int r = 0; r < 4; r++) {
                int o = o0 + w * 32 + os * 16 + quad * 4 + r;
                size_t idx = (size_t)b * CI * HWD + (size_t)o * HWD + hw0 + mt * 16 + ln;
                out[idx] = s[os][mt][r] + Wb[o] + x[idx];
            }
}

extern "C" void kernel_launch(void* const* d_in, const int* in_sizes, int n_in,
                              void* d_out, int out_size, void* d_ws, size_t ws_size,
                              hipStream_t stream)
{
    const float* x  = (const float*)d_in[0];
    const float* tw = (const float*)d_in[1];
    const float* tb = (const float*)d_in[2];
    const float* pw = (const float*)d_in[3];
    const float* pb = (const float*)d_in[4];
    const float* gw = (const float*)d_in[5];
    const float* gb = (const float*)d_in[6];
    const float* Ww = (const float*)d_in[7];
    const float* Wb = (const float*)d_in[8];
    unsigned short* wsu = (unsigned short*)d_ws;
    float* wsf = (float*)d_ws;
    unsigned short* thetaB = wsu + U_THETA;
    unsigned short* phiTB  = wsu + U_PHIT;
    unsigned short* gB     = wsu + U_G;
    unsigned short* gTB    = wsu + U_GT;
    unsigned short* Ybuf   = wsu + U_Y;
    unsigned short* xTB    = wsu + U_XT;
    unsigned short* wcatB  = wsu + U_WCAT;
    unsigned short* wwB    = wsu + U_WW;
    float* Dbuf = wsf + F_D;
    float* out = (float*)d_out;
    dim3 blk(256, 1, 1);
    hipLaunchKernelGGL(k0_xpose, dim3(64, 4, NBATCH), blk, 0, stream, x, xTB);
    hipLaunchKernelGGL(k0_weights, dim3(128, 1, 1), blk, 0, stream,
                       tw, pw, gw, Ww, wcatB, wwB);
    hipLaunchKernelGGL(k1_mfma, dim3(64, 6, NBATCH), blk, 0, stream,
                       xTB, wcatB, tb, pb, gb, thetaB, phiTB, gB);
    hipLaunchKernelGGL(k2_colsum, dim3(64, 4, NBATCH), blk, 0, stream,
                       thetaB, phiTB, Dbuf);
    hipLaunchKernelGGL(k1b_transpose_scale_g, dim3(128, 1, NBATCH), blk, 0, stream,
                       gB, Dbuf, gTB);
    hipLaunchKernelGGL(k3_attn, dim3(64, 4, NBATCH), blk, 0, stream,
                       thetaB, phiTB, gTB, Ybuf);
    hipLaunchKernelGGL(k4_mfma, dim3(64, 2, NBATCH), blk, 0, stream,
                       x, wwB, Wb, Ybuf, out);
}